// Round 5
// baseline (2498.473 us; speedup 1.0000x reference)
//
#include <hip/hip_runtime.h>
#include <math.h>

// GIN: agg commutes with first linear -> z = x@w1 precomputed (bf16).
// Agg kernel v2: flat edge stream + LDS fp32 atomic accumulate (ds_add_f32),
// no local CSR, sentinel-padded edge lists (zero z row) -> branch-free 8-deep
// ILP gather. acc layout [feat][node] stride 129 -> conflict-free banks.

#define NNODES 100000
#define NEDGES 1600000
#define NGRAPHS 512
#define NB 782      // ceil(100000/128)
#define BCAP 2560   // mult of 64; mean 2046, sd 45 -> +11 sigma
#define CHUNK 8192
#define NCHUNKS 196  // ceil(1600000/8192)
#define SENT (NNODES << 7)  // sentinel edge: src=NNODES (zero row), dst_local=0

typedef unsigned short u16;

__device__ __forceinline__ u16 f2b(float f) {
  union { float f; unsigned u; } v;
  v.f = f;
  unsigned r = v.u + 0x7FFF + ((v.u >> 16) & 1);  // RN-even
  return (u16)(r >> 16);
}
__device__ __forceinline__ float b2f(u16 h) {
  union { unsigned u; float f; } v;
  v.u = ((unsigned)h) << 16;
  return v.f;
}

// ---------------- init: gcur + zero rows of zA/zB ----------------

__global__ __launch_bounds__(256) void init_kernel(int* __restrict__ gcur,
                                                   u16* __restrict__ zA,
                                                   u16* __restrict__ zB) {
  int i = blockIdx.x * 256 + threadIdx.x;
  if (i < NB) gcur[i] = i * BCAP;
  if (blockIdx.x == 3) {  // 768..1023: zero row NNODES of zA/zB (64 each)
    int t = threadIdx.x;
    if (t < 64) zA[(size_t)NNODES * 64 + t] = 0;
    else if (t < 128) zB[(size_t)NNODES * 64 + (t - 64)] = 0;
  }
}

// ---------------- binned scatter ----------------

__global__ __launch_bounds__(512) void bin_kernel(const int* __restrict__ src,
                                                  const int* __restrict__ dst,
                                                  int* __restrict__ gcur,
                                                  int* __restrict__ st) {
  __shared__ int hist[NB];
  __shared__ int lofs[NB + 1];
  __shared__ int lcur[NB];
  __shared__ int gbase[NB];
  __shared__ int sd[1024];
  __shared__ int staged[CHUNK];
  __shared__ u16 stb[CHUNK];
  const int t = threadIdx.x;
  const int e0 = blockIdx.x * CHUNK;
  const int n = min(CHUNK, NEDGES - e0);

  for (int i = t; i < NB; i += 512) hist[i] = 0;
  __syncthreads();

  int pk[16];
  int bk[16];
#pragma unroll
  for (int k = 0; k < 16; ++k) {
    int i = t + k * 512;
    if (i < n) {
      int s = src[e0 + i];
      int d = dst[e0 + i];
      int b = d >> 7;
      pk[k] = (s << 7) | (d & 127);
      bk[k] = b;
      atomicAdd(&hist[b], 1);
    } else {
      bk[k] = -1;
    }
  }
  __syncthreads();

  sd[t] = (t < NB) ? hist[t] : 0;
  sd[t + 512] = (t + 512 < NB) ? hist[t + 512] : 0;
  __syncthreads();
  for (int off = 1; off < 1024; off <<= 1) {
    int v0 = (t >= off) ? sd[t - off] : 0;
    int v1 = (t + 512 >= off) ? sd[t + 512 - off] : 0;
    __syncthreads();
    sd[t] += v0;
    sd[t + 512] += v1;
    __syncthreads();
  }
  if (t == 0) lofs[0] = 0;
  for (int i = t; i < NB; i += 512) {
    int inc = sd[i];
    int c = hist[i];
    lofs[i + 1] = inc;
    lcur[i] = inc - c;
    gbase[i] = c ? atomicAdd(&gcur[i], c) : 0;
  }
  __syncthreads();

#pragma unroll
  for (int k = 0; k < 16; ++k) {
    if (bk[k] >= 0) {
      int r = atomicAdd(&lcur[bk[k]], 1);
      staged[r] = pk[k];
      stb[r] = (u16)bk[k];
    }
  }
  __syncthreads();

  for (int i = t; i < n; i += 512) {
    int b = stb[i];
    st[gbase[b] + (i - lofs[b])] = staged[i];
  }
}

// ---------------- pad each bucket's edge list to mult of 64 ----------------

__global__ __launch_bounds__(64) void pad_kernel(const int* __restrict__ gcur,
                                                 int* __restrict__ st) {
  int b = blockIdx.x;
  int end = gcur[b];
  int ofs = b * BCAP;
  int cnt = end - ofs;
  int S = (cnt + 63) & ~63;
  if (S > BCAP) S = BCAP;
  int pos = end + threadIdx.x;
  if (pos < ofs + S) st[pos] = SENT;
}

// ---------------- GEMM: z = x(Nx128) @ w1(128x64), z bf16 ----------------

__global__ __launch_bounds__(512) void gemm128_kernel(
    const float* __restrict__ x, const float* __restrict__ w1,
    u16* __restrict__ z) {
  __shared__ u16 w1h[128 * 64];
  __shared__ float rows[8][128 * 4];
  int tid = threadIdx.x;
  for (int i = tid; i < 128 * 64; i += 512) w1h[i] = f2b(w1[i]);
  __syncthreads();
  const int lane = tid & 63;
  const int wv = tid >> 6;
  float* myrows = rows[wv];
  const int n0 = (blockIdx.x * 8 + wv) * 4;

  float lo[4], hi[4];
#pragma unroll
  for (int j = 0; j < 4; ++j) {
    lo[j] = x[(size_t)(n0 + j) * 128 + lane];
    hi[j] = x[(size_t)(n0 + j) * 128 + 64 + lane];
  }
  *(float4*)&myrows[lane * 4] = make_float4(lo[0], lo[1], lo[2], lo[3]);
  *(float4*)&myrows[(64 + lane) * 4] = make_float4(hi[0], hi[1], hi[2], hi[3]);
  __asm__ volatile("s_waitcnt lgkmcnt(0)" ::: "memory");

  float acc[4] = {0.f, 0.f, 0.f, 0.f};
#pragma unroll 8
  for (int k = 0; k < 128; ++k) {
    float4 r = *(const float4*)&myrows[k * 4];
    float w = b2f(w1h[k * 64 + lane]);
    acc[0] += r.x * w;
    acc[1] += r.y * w;
    acc[2] += r.z * w;
    acc[3] += r.w * w;
  }
#pragma unroll
  for (int j = 0; j < 4; ++j) z[(size_t)(n0 + j) * 64 + lane] = f2b(acc[j]);
}

// ---------------- agg v2: flat edges + LDS atomic acc ----------------

template <bool HAS_NEXT>
__global__ __launch_bounds__(512) void agg_kernel(
    const u16* __restrict__ zin, const float* __restrict__ b1,
    const float* __restrict__ w2, const float* __restrict__ b2,
    const float* __restrict__ w1n, const float* __restrict__ eps, int li,
    const int* __restrict__ gcur, const int* __restrict__ st,
    u16* __restrict__ hout, u16* __restrict__ zn) {
  __shared__ float acc[64 * 129];  // [feat][node], stride 129 -> bank (f+d)&31
  __shared__ u16 w2h[64 * 64];     // 8 KB
  __shared__ u16 w1nh[HAS_NEXT ? 64 * 64 : 2];
  const int tid = threadIdx.x;
  const int lane = tid & 63;
  const int wv = tid >> 6;
  const int b = blockIdx.x;
  const int base = b << 7;
  const int ofs = b * BCAP;
  const int cnt = min(gcur[b] - ofs, BCAP);
  const int S = min((cnt + 63) & ~63, BCAP);
  const int W = S >> 3;  // per-wave span, mult of 8

  for (int i = tid; i < 64 * 64; i += 512) {
    w2h[i] = f2b(w2[i]);
    if (HAS_NEXT) w1nh[i] = f2b(w1n[i]);
  }

  // acc init: (1+eps)*z_self + b1  (clamped to zero row beyond N)
  const float e1 = 1.0f + eps[li];
  const float b1v = b1[lane];
#pragma unroll
  for (int it = 0; it < 16; ++it) {
    int d = (tid >> 6) + it * 8;
    int nn = base + d;
    if (nn > NNODES) nn = NNODES;  // zero row
    float zv = b2f(zin[(size_t)nn * 64 + lane]);
    acc[lane * 129 + d] = e1 * zv + b1v;
  }
  __syncthreads();

  // flat edge stream: 8-deep ILP, no branches (sentinel-padded)
  const int* eptr = st + ofs + wv * W;
  for (int i = 0; i < W; i += 8) {
    int4 pa = *(const int4*)(eptr + i);      // wave-uniform 16B fetch
    int4 pb = *(const int4*)(eptr + i + 4);
    float v0 = b2f(zin[(size_t)(pa.x >> 7) * 64 + lane]);
    float v1 = b2f(zin[(size_t)(pa.y >> 7) * 64 + lane]);
    float v2 = b2f(zin[(size_t)(pa.z >> 7) * 64 + lane]);
    float v3 = b2f(zin[(size_t)(pa.w >> 7) * 64 + lane]);
    float v4 = b2f(zin[(size_t)(pb.x >> 7) * 64 + lane]);
    float v5 = b2f(zin[(size_t)(pb.y >> 7) * 64 + lane]);
    float v6 = b2f(zin[(size_t)(pb.z >> 7) * 64 + lane]);
    float v7 = b2f(zin[(size_t)(pb.w >> 7) * 64 + lane]);
    atomicAdd(&acc[lane * 129 + (pa.x & 127)], v0);
    atomicAdd(&acc[lane * 129 + (pa.y & 127)], v1);
    atomicAdd(&acc[lane * 129 + (pa.z & 127)], v2);
    atomicAdd(&acc[lane * 129 + (pa.w & 127)], v3);
    atomicAdd(&acc[lane * 129 + (pb.x & 127)], v4);
    atomicAdd(&acc[lane * 129 + (pb.y & 127)], v5);
    atomicAdd(&acc[lane * 129 + (pb.z & 127)], v6);
    atomicAdd(&acc[lane * 129 + (pb.w & 127)], v7);
  }
  __syncthreads();

  // relu sweep: h1 = relu(acc)
  for (int i = tid; i < 64 * 129; i += 512) acc[i] = fmaxf(acc[i], 0.f);
  __syncthreads();

  // MLP: per wave 4 nodes per pass; lane = out-feature
  const float b2v = b2[lane];
#pragma unroll 1
  for (int pass = 0; pass < 4; ++pass) {
    const int ln0 = pass * 32 + wv * 4;
    float o0 = b2v, o1 = b2v, o2 = b2v, o3 = b2v;
#pragma unroll 8
    for (int k = 0; k < 64; ++k) {
      const float* ap = &acc[k * 129 + ln0];  // broadcast reads
      float r0 = ap[0], r1 = ap[1], r2 = ap[2], r3 = ap[3];
      float w = b2f(w2h[k * 64 + lane]);
      o0 += r0 * w;
      o1 += r1 * w;
      o2 += r2 * w;
      o3 += r3 * w;
    }
    o0 = fmaxf(o0, 0.f);
    o1 = fmaxf(o1, 0.f);
    o2 = fmaxf(o2, 0.f);
    o3 = fmaxf(o3, 0.f);
    int nn = base + ln0;
    if (nn + 3 < NNODES) {
      hout[(size_t)(nn + 0) * 64 + lane] = f2b(o0);
      hout[(size_t)(nn + 1) * 64 + lane] = f2b(o1);
      hout[(size_t)(nn + 2) * 64 + lane] = f2b(o2);
      hout[(size_t)(nn + 3) * 64 + lane] = f2b(o3);
    } else {
      if (nn + 0 < NNODES) hout[(size_t)(nn + 0) * 64 + lane] = f2b(o0);
      if (nn + 1 < NNODES) hout[(size_t)(nn + 1) * 64 + lane] = f2b(o1);
      if (nn + 2 < NNODES) hout[(size_t)(nn + 2) * 64 + lane] = f2b(o2);
      if (nn + 3 < NNODES) hout[(size_t)(nn + 3) * 64 + lane] = f2b(o3);
    }

    if (HAS_NEXT) {
      __asm__ volatile("s_waitcnt lgkmcnt(0)" ::: "memory");
      // overwrite own columns with h (safe: only this wave touches them)
      acc[lane * 129 + ln0 + 0] = o0;
      acc[lane * 129 + ln0 + 1] = o1;
      acc[lane * 129 + ln0 + 2] = o2;
      acc[lane * 129 + ln0 + 3] = o3;
      __asm__ volatile("s_waitcnt lgkmcnt(0)" ::: "memory");
      float q0 = 0.f, q1 = 0.f, q2 = 0.f, q3 = 0.f;
#pragma unroll 8
      for (int k = 0; k < 64; ++k) {
        const float* ap = &acc[k * 129 + ln0];
        float r0 = ap[0], r1 = ap[1], r2 = ap[2], r3 = ap[3];
        float w = b2f(w1nh[k * 64 + lane]);
        q0 += r0 * w;
        q1 += r1 * w;
        q2 += r2 * w;
        q3 += r3 * w;
      }
      if (nn + 3 < NNODES) {
        zn[(size_t)(nn + 0) * 64 + lane] = f2b(q0);
        zn[(size_t)(nn + 1) * 64 + lane] = f2b(q1);
        zn[(size_t)(nn + 2) * 64 + lane] = f2b(q2);
        zn[(size_t)(nn + 3) * 64 + lane] = f2b(q3);
      } else {
        if (nn + 0 < NNODES) zn[(size_t)(nn + 0) * 64 + lane] = f2b(q0);
        if (nn + 1 < NNODES) zn[(size_t)(nn + 1) * 64 + lane] = f2b(q1);
        if (nn + 2 < NNODES) zn[(size_t)(nn + 2) * 64 + lane] = f2b(q2);
        if (nn + 3 < NNODES) zn[(size_t)(nn + 3) * 64 + lane] = f2b(q3);
      }
    }
  }
}

// ---------------- Per-graph pooling (batch sorted, h bf16) ----------------

__device__ __forceinline__ int lower_bound(const int* __restrict__ a, int n,
                                           int v) {
  int lo = 0, hi = n;
  while (lo < hi) {
    int m = (lo + hi) >> 1;
    if (a[m] < v)
      lo = m + 1;
    else
      hi = m;
  }
  return lo;
}

__global__ __launch_bounds__(256) void pool_kernel(const u16* __restrict__ h,
                                                   const int* __restrict__ batch,
                                                   float* __restrict__ g,
                                                   int li) {
  int gi = blockIdx.x;
  int tid = threadIdx.x;
  int sub = tid >> 6, f = tid & 63;
  int s = lower_bound(batch, NNODES, gi);
  int e = lower_bound(batch, NNODES, gi + 1);
  float sum = 0.f, mx = -3.0e38f;
  for (int n = s + sub; n < e; n += 4) {
    float v = b2f(h[(size_t)n * 64 + f]);
    sum += v;
    mx = fmaxf(mx, v);
  }
  __shared__ float ssum[4][64];
  __shared__ float smax[4][64];
  ssum[sub][f] = sum;
  smax[sub][f] = mx;
  __syncthreads();
  if (tid < 64) {
    float S = ssum[0][f] + ssum[1][f] + ssum[2][f] + ssum[3][f];
    float M = fmaxf(fmaxf(smax[0][f], smax[1][f]), fmaxf(smax[2][f], smax[3][f]));
    int cnt = e - s;
    float mean = S / fmaxf((float)cnt, 1.0f);
    int base = gi * 576 + li * 64 + f;
    g[base] = mean;
    g[base + 192] = M;
    g[base + 384] = S;
  }
}

// ---------------- Head ----------------

__global__ __launch_bounds__(256) void head_kernel(
    const float* __restrict__ g, const float* __restrict__ fc1w,
    const float* __restrict__ fc1b, const float* __restrict__ fc2w,
    const float* __restrict__ fc2b, float* __restrict__ out) {
  __shared__ float gs[4 * 576];
  int tid = threadIdx.x;
  int g0 = blockIdx.x * 4;
  for (int i = tid; i < 4 * 576; i += 256) gs[i] = g[g0 * 576 + i];
  __syncthreads();
  int wv = tid >> 6, lane = tid & 63;
  int gi = g0 + wv;
  const float* grow = &gs[wv * 576];
  float acc = fc1b[lane];
#pragma unroll 8
  for (int k = 0; k < 576; ++k) acc += grow[k] * fc1w[k * 64 + lane];
  acc = fmaxf(acc, 0.f);
  float p0 = acc * fc2w[lane * 2 + 0];
  float p1 = acc * fc2w[lane * 2 + 1];
  for (int off = 32; off; off >>= 1) {
    p0 += __shfl_down(p0, off);
    p1 += __shfl_down(p1, off);
  }
  if (lane == 0) {
    out[gi * 2 + 0] = 1.f / (1.f + __expf(-(p0 + fc2b[0])));
    out[gi * 2 + 1] = 1.f / (1.f + __expf(-(p1 + fc2b[1])));
  }
}

// ---------------- launch ----------------

extern "C" void kernel_launch(void* const* d_in, const int* in_sizes, int n_in,
                              void* d_out, int out_size, void* d_ws,
                              size_t ws_size, hipStream_t stream) {
  const float* x = (const float*)d_in[0];
  const int* ei = (const int*)d_in[1];
  const int* src = ei;
  const int* dst = ei + NEDGES;
  const int* batch = (const int*)d_in[2];
  const float* lw1[3] = {(const float*)d_in[3], (const float*)d_in[7],
                         (const float*)d_in[11]};
  const float* lb1[3] = {(const float*)d_in[4], (const float*)d_in[8],
                         (const float*)d_in[12]};
  const float* lw2[3] = {(const float*)d_in[5], (const float*)d_in[9],
                         (const float*)d_in[13]};
  const float* lb2[3] = {(const float*)d_in[6], (const float*)d_in[10],
                         (const float*)d_in[14]};
  const float* eps = (const float*)d_in[15];
  const float* fc1w = (const float*)d_in[16];
  const float* fc1b = (const float*)d_in[17];
  const float* fc2w = (const float*)d_in[18];
  const float* fc2b = (const float*)d_in[19];
  float* out = (float*)d_out;

  char* p = (char*)d_ws;
  auto carve = [&](size_t bytes) {
    void* r = (void*)p;
    p += (bytes + 1023) & ~(size_t)1023;
    return r;
  };
  int* gcur = (int*)carve((NB + 4) * 4);
  int* st = (int*)carve((size_t)NB * BCAP * 4);
  u16* zA = (u16*)carve((size_t)(NNODES + 1) * 64 * 2);
  u16* zB = (u16*)carve((size_t)(NNODES + 1) * 64 * 2);
  u16* hA = (u16*)carve((size_t)NNODES * 64 * 2);
  float* g = (float*)carve((size_t)NGRAPHS * 576 * 4);

  init_kernel<<<4, 256, 0, stream>>>(gcur, zA, zB);
  bin_kernel<<<NCHUNKS, 512, 0, stream>>>(src, dst, gcur, st);
  pad_kernel<<<NB, 64, 0, stream>>>(gcur, st);

  gemm128_kernel<<<3125, 512, 0, stream>>>(x, lw1[0], zA);

  agg_kernel<true><<<NB, 512, 0, stream>>>(zA, lb1[0], lw2[0], lb2[0], lw1[1],
                                           eps, 0, gcur, st, hA, zB);
  pool_kernel<<<NGRAPHS, 256, 0, stream>>>(hA, batch, g, 0);

  agg_kernel<true><<<NB, 512, 0, stream>>>(zB, lb1[1], lw2[1], lb2[1], lw1[2],
                                           eps, 1, gcur, st, hA, zA);
  pool_kernel<<<NGRAPHS, 256, 0, stream>>>(hA, batch, g, 1);

  agg_kernel<false><<<NB, 512, 0, stream>>>(zA, lb1[2], lw2[2], lb2[2],
                                            (const float*)nullptr, eps, 2, gcur,
                                            st, hA, (u16*)nullptr);
  pool_kernel<<<NGRAPHS, 256, 0, stream>>>(hA, batch, g, 2);

  head_kernel<<<NGRAPHS / 4, 256, 0, stream>>>(g, fc1w, fc1b, fc2w, fc2b, out);
}

// Round 6
// 504.987 us; speedup vs baseline: 4.9476x; 4.9476x over previous
//
#include <hip/hip_runtime.h>
#include <math.h>

// GIN: agg commutes with first linear -> z = x@w1 precomputed (bf16).
// Agg v3: half-bucket blocks (64 nodes, 256 thr) -> 1564 blocks (~5/CU
// resident), local CSR in LDS with per-node segments PADDED to mult-8
// (sentinel col = zero row) -> branch-free 8-deep gather ILP.
// NO LDS float atomics (R5 lesson: ds_add_f32 in hot loop = 6x regression).

#define NNODES 100000
#define NEDGES 1600000
#define NGRAPHS 512
#define NB 782       // ceil(100000/128)  (staging buckets of 128 dst)
#define NBH 1564     // 2 half-buckets (64 nodes) per bucket
#define BCAP 2560    // per-bucket staging capacity (mean 2046, sd 45)
#define LCAP 1792    // half-bucket padded CSR cap: ~1300 + 64*7
#define CHUNK 4096
#define NCHUNKS 391  // ceil(1600000/4096)

typedef unsigned short u16;

__device__ __forceinline__ u16 f2b(float f) {
  union { float f; unsigned u; } v;
  v.f = f;
  unsigned r = v.u + 0x7FFF + ((v.u >> 16) & 1);  // RN-even
  return (u16)(r >> 16);
}
__device__ __forceinline__ float b2f(u16 h) {
  union { unsigned u; float f; } v;
  v.u = ((unsigned)h) << 16;
  return v.f;
}

// ---------------- init: gcur + zero rows of zA/zB ----------------

__global__ __launch_bounds__(256) void init_kernel(int* __restrict__ gcur,
                                                   u16* __restrict__ zA,
                                                   u16* __restrict__ zB) {
  int i = blockIdx.x * 256 + threadIdx.x;
  if (i < NB) gcur[i] = i * BCAP;
  if (blockIdx.x == 3) {
    int t = threadIdx.x;
    if (t < 64) zA[(size_t)NNODES * 64 + t] = 0;
    else if (t < 128) zB[(size_t)NNODES * 64 + (t - 64)] = 0;
  }
}

// ---------------- binned scatter (128-node buckets) ----------------

__global__ __launch_bounds__(512) void bin_kernel(const int* __restrict__ src,
                                                  const int* __restrict__ dst,
                                                  int* __restrict__ gcur,
                                                  int* __restrict__ st) {
  __shared__ int hist[NB];
  __shared__ int lofs[NB + 1];
  __shared__ int lcur[NB];
  __shared__ int gbase[NB];
  __shared__ int sd[1024];
  __shared__ int staged[CHUNK];
  __shared__ u16 stb[CHUNK];
  const int t = threadIdx.x;
  const int e0 = blockIdx.x * CHUNK;
  const int n = min(CHUNK, NEDGES - e0);

  for (int i = t; i < NB; i += 512) hist[i] = 0;
  __syncthreads();

  int pk[8];
  int bk[8];
#pragma unroll
  for (int k = 0; k < 8; ++k) {
    int i = t + k * 512;
    if (i < n) {
      int s = src[e0 + i];
      int d = dst[e0 + i];
      int b = d >> 7;
      pk[k] = (s << 7) | (d & 127);
      bk[k] = b;
      atomicAdd(&hist[b], 1);
    } else {
      bk[k] = -1;
    }
  }
  __syncthreads();

  sd[t] = (t < NB) ? hist[t] : 0;
  sd[t + 512] = (t + 512 < NB) ? hist[t + 512] : 0;
  __syncthreads();
  for (int off = 1; off < 1024; off <<= 1) {
    int v0 = (t >= off) ? sd[t - off] : 0;
    int v1 = (t + 512 >= off) ? sd[t + 512 - off] : 0;
    __syncthreads();
    sd[t] += v0;
    sd[t + 512] += v1;
    __syncthreads();
  }
  if (t == 0) lofs[0] = 0;
  for (int i = t; i < NB; i += 512) {
    int inc = sd[i];
    int c = hist[i];
    lofs[i + 1] = inc;
    lcur[i] = inc - c;
    gbase[i] = c ? atomicAdd(&gcur[i], c) : 0;
  }
  __syncthreads();

#pragma unroll
  for (int k = 0; k < 8; ++k) {
    if (bk[k] >= 0) {
      int r = atomicAdd(&lcur[bk[k]], 1);
      staged[r] = pk[k];
      stb[r] = (u16)bk[k];
    }
  }
  __syncthreads();

  for (int i = t; i < n; i += 512) {
    int b = stb[i];
    st[gbase[b] + (i - lofs[b])] = staged[i];
  }
}

// ---------------- GEMM: z = x(Nx128) @ w1(128x64), z bf16 ----------------

__global__ __launch_bounds__(512) void gemm128_kernel(
    const float* __restrict__ x, const float* __restrict__ w1,
    u16* __restrict__ z) {
  __shared__ u16 w1h[128 * 64];
  __shared__ float rows[8][128 * 4];
  int tid = threadIdx.x;
  for (int i = tid; i < 128 * 64; i += 512) w1h[i] = f2b(w1[i]);
  __syncthreads();
  const int lane = tid & 63;
  const int wv = tid >> 6;
  float* myrows = rows[wv];
  const int n0 = (blockIdx.x * 8 + wv) * 4;

  float lo[4], hi[4];
#pragma unroll
  for (int j = 0; j < 4; ++j) {
    lo[j] = x[(size_t)(n0 + j) * 128 + lane];
    hi[j] = x[(size_t)(n0 + j) * 128 + 64 + lane];
  }
  *(float4*)&myrows[lane * 4] = make_float4(lo[0], lo[1], lo[2], lo[3]);
  *(float4*)&myrows[(64 + lane) * 4] = make_float4(hi[0], hi[1], hi[2], hi[3]);
  __asm__ volatile("s_waitcnt lgkmcnt(0)" ::: "memory");

  float acc[4] = {0.f, 0.f, 0.f, 0.f};
#pragma unroll 8
  for (int k = 0; k < 128; ++k) {
    float4 r = *(const float4*)&myrows[k * 4];
    float w = b2f(w1h[k * 64 + lane]);
    acc[0] += r.x * w;
    acc[1] += r.y * w;
    acc[2] += r.z * w;
    acc[3] += r.w * w;
  }
#pragma unroll
  for (int j = 0; j < 4; ++j) z[(size_t)(n0 + j) * 64 + lane] = f2b(acc[j]);
}

// ---------------- agg v3: half-bucket, padded CSR, 8-deep gather ----------

template <bool HAS_NEXT>
__global__ __launch_bounds__(256) void agg_kernel(
    const u16* __restrict__ zin, const float* __restrict__ b1,
    const float* __restrict__ w2, const float* __restrict__ b2,
    const float* __restrict__ w1n, const float* __restrict__ eps, int li,
    const int* __restrict__ gcur, const int* __restrict__ st,
    u16* __restrict__ hout, u16* __restrict__ zn) {
  __shared__ u16 w2h[64 * 64];  // 8 KB
  __shared__ u16 w1nh[HAS_NEXT ? 64 * 64 : 2];
  __shared__ int lcol[LCAP];  // 7 KB
  __shared__ int lhist[64];
  __shared__ int lofs[65];
  __shared__ int lcur[64];
  __shared__ int ssc[64];
  __shared__ float rows[4][256];  // 4 KB
  const int tid = threadIdx.x;
  const int lane = tid & 63;
  const int wv = tid >> 6;
  const int blk = blockIdx.x;
  const int bkt = blk >> 1;
  const int half = blk & 1;
  const int base = (bkt << 7) + (half << 6);  // first node of this half
  const int ofs = bkt * BCAP;
  const int cnt = min(gcur[bkt] - ofs, BCAP);

  for (int i = tid; i < 64 * 64; i += 256) {
    w2h[i] = f2b(w2[i]);
    if (HAS_NEXT) w1nh[i] = f2b(w1n[i]);
  }
  if (tid < 64) lhist[tid] = 0;
  __syncthreads();

  // histogram of this half's 64 dst slots
  for (int i = tid; i < cnt; i += 256) {
    int d7 = st[ofs + i] & 127;
    if ((d7 >> 6) == half) atomicAdd(&lhist[d7 & 63], 1);
  }
  __syncthreads();
  // inclusive scan of padded counts (mult-8)
  if (tid < 64) ssc[tid] = (lhist[tid] + 7) & ~7;
  __syncthreads();
  for (int off = 1; off < 64; off <<= 1) {
    int v = (tid < 64 && tid >= off) ? ssc[tid - off] : 0;
    __syncthreads();
    if (tid < 64) ssc[tid] += v;
    __syncthreads();
  }
  if (tid < 64) {
    lofs[tid + 1] = ssc[tid];
    lcur[tid] = ssc[tid] - ((lhist[tid] + 7) & ~7);
  }
  if (tid == 0) lofs[0] = 0;
  __syncthreads();
  // CSR fill
  for (int i = tid; i < cnt; i += 256) {
    int p = st[ofs + i];
    int d7 = p & 127;
    if ((d7 >> 6) == half) {
      int r = atomicAdd(&lcur[d7 & 63], 1);
      lcol[r] = p >> 7;
    }
  }
  __syncthreads();
  // sentinel-pad each node's tail to its mult-8 boundary
  if (tid < 64) {
    for (int r = lcur[tid]; r < lofs[tid + 1]; ++r) lcol[r] = NNODES;
  }
  __syncthreads();

  const float e1 = 1.0f + eps[li];
  const float b1v = b1[lane];
  const float b2v = b2[lane];
  float* myrows = rows[wv];

#pragma unroll 1
  for (int pass = 0; pass < 4; ++pass) {
    const int ln0 = pass * 16 + wv * 4;
    float a[4];
#pragma unroll
    for (int j = 0; j < 4; ++j) {
      int ln = ln0 + j;
      int nn = base + ln;
      int sn = (nn < NNODES) ? nn : NNODES;
      int rs = lofs[ln], re = lofs[ln + 1];
      float s0 = 0.f, s1 = 0.f, s2 = 0.f, s3 = 0.f;
      float s4 = 0.f, s5 = 0.f, s6 = 0.f, s7 = 0.f;
      for (int e = rs; e < re; e += 8) {
        int4 ca = *(const int4*)&lcol[e];      // lane-uniform broadcast
        int4 cb = *(const int4*)&lcol[e + 4];
        s0 += b2f(zin[(size_t)ca.x * 64 + lane]);
        s1 += b2f(zin[(size_t)ca.y * 64 + lane]);
        s2 += b2f(zin[(size_t)ca.z * 64 + lane]);
        s3 += b2f(zin[(size_t)ca.w * 64 + lane]);
        s4 += b2f(zin[(size_t)cb.x * 64 + lane]);
        s5 += b2f(zin[(size_t)cb.y * 64 + lane]);
        s6 += b2f(zin[(size_t)cb.z * 64 + lane]);
        s7 += b2f(zin[(size_t)cb.w * 64 + lane]);
      }
      float self = b2f(zin[(size_t)sn * 64 + lane]);
      a[j] = ((s0 + s1) + (s2 + s3)) + ((s4 + s5) + (s6 + s7)) + e1 * self;
    }
#pragma unroll
    for (int j = 0; j < 4; ++j) a[j] = fmaxf(a[j] + b1v, 0.f);
    *(float4*)&myrows[lane * 4] = make_float4(a[0], a[1], a[2], a[3]);
    __asm__ volatile("s_waitcnt lgkmcnt(0)" ::: "memory");

    float o0 = b2v, o1 = b2v, o2 = b2v, o3 = b2v;
#pragma unroll 8
    for (int k = 0; k < 64; ++k) {
      float4 r = *(const float4*)&myrows[k * 4];  // broadcast
      float w = b2f(w2h[k * 64 + lane]);
      o0 += r.x * w;
      o1 += r.y * w;
      o2 += r.z * w;
      o3 += r.w * w;
    }
    o0 = fmaxf(o0, 0.f);
    o1 = fmaxf(o1, 0.f);
    o2 = fmaxf(o2, 0.f);
    o3 = fmaxf(o3, 0.f);
    int nn = base + ln0;
    if (nn + 0 < NNODES) hout[(size_t)(nn + 0) * 64 + lane] = f2b(o0);
    if (nn + 1 < NNODES) hout[(size_t)(nn + 1) * 64 + lane] = f2b(o1);
    if (nn + 2 < NNODES) hout[(size_t)(nn + 2) * 64 + lane] = f2b(o2);
    if (nn + 3 < NNODES) hout[(size_t)(nn + 3) * 64 + lane] = f2b(o3);

    if (HAS_NEXT) {
      __asm__ volatile("s_waitcnt lgkmcnt(0)" ::: "memory");
      *(float4*)&myrows[lane * 4] = make_float4(o0, o1, o2, o3);
      __asm__ volatile("s_waitcnt lgkmcnt(0)" ::: "memory");
      float q0 = 0.f, q1 = 0.f, q2 = 0.f, q3 = 0.f;
#pragma unroll 8
      for (int k = 0; k < 64; ++k) {
        float4 r = *(const float4*)&myrows[k * 4];
        float w = b2f(w1nh[k * 64 + lane]);
        q0 += r.x * w;
        q1 += r.y * w;
        q2 += r.z * w;
        q3 += r.w * w;
      }
      if (nn + 0 < NNODES) zn[(size_t)(nn + 0) * 64 + lane] = f2b(q0);
      if (nn + 1 < NNODES) zn[(size_t)(nn + 1) * 64 + lane] = f2b(q1);
      if (nn + 2 < NNODES) zn[(size_t)(nn + 2) * 64 + lane] = f2b(q2);
      if (nn + 3 < NNODES) zn[(size_t)(nn + 3) * 64 + lane] = f2b(q3);
    }
    __asm__ volatile("s_waitcnt lgkmcnt(0)" ::: "memory");
  }
}

// ---------------- Per-graph pooling (batch sorted, h bf16) ----------------

__device__ __forceinline__ int lower_bound(const int* __restrict__ a, int n,
                                           int v) {
  int lo = 0, hi = n;
  while (lo < hi) {
    int m = (lo + hi) >> 1;
    if (a[m] < v)
      lo = m + 1;
    else
      hi = m;
  }
  return lo;
}

__global__ __launch_bounds__(256) void pool_kernel(const u16* __restrict__ h,
                                                   const int* __restrict__ batch,
                                                   float* __restrict__ g,
                                                   int li) {
  int gi = blockIdx.x;
  int tid = threadIdx.x;
  int sub = tid >> 6, f = tid & 63;
  int s = lower_bound(batch, NNODES, gi);
  int e = lower_bound(batch, NNODES, gi + 1);
  float sum = 0.f, mx = -3.0e38f;
  for (int n = s + sub; n < e; n += 4) {
    float v = b2f(h[(size_t)n * 64 + f]);
    sum += v;
    mx = fmaxf(mx, v);
  }
  __shared__ float ssum[4][64];
  __shared__ float smax[4][64];
  ssum[sub][f] = sum;
  smax[sub][f] = mx;
  __syncthreads();
  if (tid < 64) {
    float S = ssum[0][f] + ssum[1][f] + ssum[2][f] + ssum[3][f];
    float M = fmaxf(fmaxf(smax[0][f], smax[1][f]), fmaxf(smax[2][f], smax[3][f]));
    int cnt = e - s;
    float mean = S / fmaxf((float)cnt, 1.0f);
    int base = gi * 576 + li * 64 + f;
    g[base] = mean;
    g[base + 192] = M;
    g[base + 384] = S;
  }
}

// ---------------- Head ----------------

__global__ __launch_bounds__(256) void head_kernel(
    const float* __restrict__ g, const float* __restrict__ fc1w,
    const float* __restrict__ fc1b, const float* __restrict__ fc2w,
    const float* __restrict__ fc2b, float* __restrict__ out) {
  __shared__ float gs[4 * 576];
  int tid = threadIdx.x;
  int g0 = blockIdx.x * 4;
  for (int i = tid; i < 4 * 576; i += 256) gs[i] = g[g0 * 576 + i];
  __syncthreads();
  int wv = tid >> 6, lane = tid & 63;
  int gi = g0 + wv;
  const float* grow = &gs[wv * 576];
  float acc = fc1b[lane];
#pragma unroll 8
  for (int k = 0; k < 576; ++k) acc += grow[k] * fc1w[k * 64 + lane];
  acc = fmaxf(acc, 0.f);
  float p0 = acc * fc2w[lane * 2 + 0];
  float p1 = acc * fc2w[lane * 2 + 1];
  for (int off = 32; off; off >>= 1) {
    p0 += __shfl_down(p0, off);
    p1 += __shfl_down(p1, off);
  }
  if (lane == 0) {
    out[gi * 2 + 0] = 1.f / (1.f + __expf(-(p0 + fc2b[0])));
    out[gi * 2 + 1] = 1.f / (1.f + __expf(-(p1 + fc2b[1])));
  }
}

// ---------------- launch ----------------

extern "C" void kernel_launch(void* const* d_in, const int* in_sizes, int n_in,
                              void* d_out, int out_size, void* d_ws,
                              size_t ws_size, hipStream_t stream) {
  const float* x = (const float*)d_in[0];
  const int* ei = (const int*)d_in[1];
  const int* src = ei;
  const int* dst = ei + NEDGES;
  const int* batch = (const int*)d_in[2];
  const float* lw1[3] = {(const float*)d_in[3], (const float*)d_in[7],
                         (const float*)d_in[11]};
  const float* lb1[3] = {(const float*)d_in[4], (const float*)d_in[8],
                         (const float*)d_in[12]};
  const float* lw2[3] = {(const float*)d_in[5], (const float*)d_in[9],
                         (const float*)d_in[13]};
  const float* lb2[3] = {(const float*)d_in[6], (const float*)d_in[10],
                         (const float*)d_in[14]};
  const float* eps = (const float*)d_in[15];
  const float* fc1w = (const float*)d_in[16];
  const float* fc1b = (const float*)d_in[17];
  const float* fc2w = (const float*)d_in[18];
  const float* fc2b = (const float*)d_in[19];
  float* out = (float*)d_out;

  char* p = (char*)d_ws;
  auto carve = [&](size_t bytes) {
    void* r = (void*)p;
    p += (bytes + 1023) & ~(size_t)1023;
    return r;
  };
  int* gcur = (int*)carve((NB + 4) * 4);
  int* st = (int*)carve((size_t)NB * BCAP * 4);
  u16* zA = (u16*)carve((size_t)(NNODES + 1) * 64 * 2);
  u16* zB = (u16*)carve((size_t)(NNODES + 1) * 64 * 2);
  u16* hA = (u16*)carve((size_t)NNODES * 64 * 2);
  float* g = (float*)carve((size_t)NGRAPHS * 576 * 4);

  init_kernel<<<4, 256, 0, stream>>>(gcur, zA, zB);
  bin_kernel<<<NCHUNKS, 512, 0, stream>>>(src, dst, gcur, st);

  gemm128_kernel<<<3125, 512, 0, stream>>>(x, lw1[0], zA);

  agg_kernel<true><<<NBH, 256, 0, stream>>>(zA, lb1[0], lw2[0], lb2[0], lw1[1],
                                            eps, 0, gcur, st, hA, zB);
  pool_kernel<<<NGRAPHS, 256, 0, stream>>>(hA, batch, g, 0);

  agg_kernel<true><<<NBH, 256, 0, stream>>>(zB, lb1[1], lw2[1], lb2[1], lw1[2],
                                            eps, 1, gcur, st, hA, zA);
  pool_kernel<<<NGRAPHS, 256, 0, stream>>>(hA, batch, g, 1);

  agg_kernel<false><<<NBH, 256, 0, stream>>>(zA, lb1[2], lw2[2], lb2[2],
                                             (const float*)nullptr, eps, 2,
                                             gcur, st, hA, (u16*)nullptr);
  pool_kernel<<<NGRAPHS, 256, 0, stream>>>(hA, batch, g, 2);

  head_kernel<<<NGRAPHS / 4, 256, 0, stream>>>(g, fc1w, fc1b, fc2w, fc2b, out);
}

// Round 7
// 467.804 us; speedup vs baseline: 5.3409x; 1.0795x over previous
//
#include <hip/hip_runtime.h>
#include <math.h>

// GIN: agg commutes with first linear -> z = x@w1 precomputed (bf16).
// v4: CSR built ONCE (csr_kernel) into global (padded mult-16 segments,
// sentinel=NNODES zero row); agg blocks int4-copy their CSR slice into LDS.
// Gather is paired-edge: half-waves take alternating edges, each lane loads
// u32=2 bf16 feats; combine with shfl_xor(32). Lane owns permuted feature
// f = 2*(lane&31)+(lane>>5). No LDS atomics in agg (R5 lesson).

#define NNODES 100000
#define NEDGES 1600000
#define NGRAPHS 512
#define NB 782       // staging buckets of 128 dst nodes
#define NBH 1564     // half-buckets (64 nodes) = agg/csr grid
#define BCAP 2560    // per-bucket staging capacity (mean 2046, sd 45)
#define LCAP 2304    // half-bucket padded CSR cap (mean ~1520, mult 16)
#define GOFS 72      // glofs row stride
#define CHUNK 4096
#define NCHUNKS 391  // ceil(1600000/4096)

typedef unsigned short u16;
typedef unsigned int u32;

__device__ __forceinline__ u16 f2b(float f) {
  union { float f; unsigned u; } v;
  v.f = f;
  unsigned r = v.u + 0x7FFF + ((v.u >> 16) & 1);  // RN-even
  return (u16)(r >> 16);
}
__device__ __forceinline__ float b2f(u16 h) {
  union { unsigned u; float f; } v;
  v.u = ((unsigned)h) << 16;
  return v.f;
}

// ---------------- init: gcur + zero rows of zA/zB ----------------

__global__ __launch_bounds__(256) void init_kernel(int* __restrict__ gcur,
                                                   u16* __restrict__ zA,
                                                   u16* __restrict__ zB) {
  int i = blockIdx.x * 256 + threadIdx.x;
  if (i < NB) gcur[i] = i * BCAP;
  if (blockIdx.x == 3) {
    int t = threadIdx.x;
    if (t < 64) zA[(size_t)NNODES * 64 + t] = 0;
    else if (t < 128) zB[(size_t)NNODES * 64 + (t - 64)] = 0;
  }
}

// ---------------- binned scatter (128-node buckets) ----------------

__global__ __launch_bounds__(512) void bin_kernel(const int* __restrict__ src,
                                                  const int* __restrict__ dst,
                                                  int* __restrict__ gcur,
                                                  int* __restrict__ st) {
  __shared__ int hist[NB];
  __shared__ int lofs[NB + 1];
  __shared__ int lcur[NB];
  __shared__ int gbase[NB];
  __shared__ int sd[1024];
  __shared__ int staged[CHUNK];
  __shared__ u16 stb[CHUNK];
  const int t = threadIdx.x;
  const int e0 = blockIdx.x * CHUNK;
  const int n = min(CHUNK, NEDGES - e0);

  for (int i = t; i < NB; i += 512) hist[i] = 0;
  __syncthreads();

  int pk[8];
  int bk[8];
#pragma unroll
  for (int k = 0; k < 8; ++k) {
    int i = t + k * 512;
    if (i < n) {
      int s = src[e0 + i];
      int d = dst[e0 + i];
      int b = d >> 7;
      pk[k] = (s << 7) | (d & 127);
      bk[k] = b;
      atomicAdd(&hist[b], 1);
    } else {
      bk[k] = -1;
    }
  }
  __syncthreads();

  sd[t] = (t < NB) ? hist[t] : 0;
  sd[t + 512] = (t + 512 < NB) ? hist[t + 512] : 0;
  __syncthreads();
  for (int off = 1; off < 1024; off <<= 1) {
    int v0 = (t >= off) ? sd[t - off] : 0;
    int v1 = (t + 512 >= off) ? sd[t + 512 - off] : 0;
    __syncthreads();
    sd[t] += v0;
    sd[t + 512] += v1;
    __syncthreads();
  }
  if (t == 0) lofs[0] = 0;
  for (int i = t; i < NB; i += 512) {
    int inc = sd[i];
    int c = hist[i];
    lofs[i + 1] = inc;
    lcur[i] = inc - c;
    gbase[i] = c ? atomicAdd(&gcur[i], c) : 0;
  }
  __syncthreads();

#pragma unroll
  for (int k = 0; k < 8; ++k) {
    if (bk[k] >= 0) {
      int r = atomicAdd(&lcur[bk[k]], 1);
      staged[r] = pk[k];
      stb[r] = (u16)bk[k];
    }
  }
  __syncthreads();

  for (int i = t; i < n; i += 512) {
    int b = stb[i];
    st[gbase[b] + (i - lofs[b])] = staged[i];
  }
}

// ---------------- CSR build (ONCE): half-bucket -> global lofs/lcol -------

__global__ __launch_bounds__(256) void csr_kernel(const int* __restrict__ gcur,
                                                  const int* __restrict__ st,
                                                  int* __restrict__ glofs,
                                                  int* __restrict__ glcol) {
  __shared__ int lcol[LCAP];
  __shared__ int lhist[64];
  __shared__ int lofs[65];
  __shared__ int lcur[64];
  __shared__ int ssc[64];
  const int tid = threadIdx.x;
  const int blk = blockIdx.x;
  const int bkt = blk >> 1;
  const int half = blk & 1;
  const int ofs = bkt * BCAP;
  const int cnt = min(gcur[bkt] - ofs, BCAP);

  if (tid < 64) lhist[tid] = 0;
  __syncthreads();
  for (int i = tid; i < cnt; i += 256) {
    int d7 = st[ofs + i] & 127;
    if ((d7 >> 6) == half) atomicAdd(&lhist[d7 & 63], 1);
  }
  __syncthreads();
  if (tid < 64) ssc[tid] = (lhist[tid] + 15) & ~15;  // pad to mult-16
  __syncthreads();
  for (int off = 1; off < 64; off <<= 1) {
    int v = (tid < 64 && tid >= off) ? ssc[tid - off] : 0;
    __syncthreads();
    if (tid < 64) ssc[tid] += v;
    __syncthreads();
  }
  if (tid < 64) {
    lofs[tid + 1] = ssc[tid];
    lcur[tid] = ssc[tid] - ((lhist[tid] + 15) & ~15);
  }
  if (tid == 0) lofs[0] = 0;
  __syncthreads();
  for (int i = tid; i < cnt; i += 256) {
    int p = st[ofs + i];
    int d7 = p & 127;
    if ((d7 >> 6) == half) {
      int r = atomicAdd(&lcur[d7 & 63], 1);
      if (r < LCAP) lcol[r] = p >> 7;
    }
  }
  __syncthreads();
  if (tid < 64) {
    int re = min(lofs[tid + 1], LCAP);
    for (int r = lcur[tid]; r < re; ++r) lcol[r] = NNODES;  // sentinel
  }
  __syncthreads();
  if (tid < 65) glofs[blk * GOFS + tid] = min(lofs[tid], LCAP);
  int L = min(lofs[64], LCAP);
  int4* gdst = (int4*)(glcol + (size_t)blk * LCAP);
  const int4* lsrc = (const int4*)lcol;
  for (int i = tid; i < (L >> 2); i += 256) gdst[i] = lsrc[i];
}

// ---------------- GEMM: z = x(Nx128) @ w1(128x64), z bf16 ----------------

__global__ __launch_bounds__(512) void gemm128_kernel(
    const float* __restrict__ x, const float* __restrict__ w1,
    u16* __restrict__ z) {
  __shared__ u16 w1h[128 * 64];
  __shared__ float rows[8][128 * 4];
  int tid = threadIdx.x;
  for (int i = tid; i < 128 * 64; i += 512) w1h[i] = f2b(w1[i]);
  __syncthreads();
  const int lane = tid & 63;
  const int wv = tid >> 6;
  float* myrows = rows[wv];
  const int n0 = (blockIdx.x * 8 + wv) * 4;

  float lo[4], hi[4];
#pragma unroll
  for (int j = 0; j < 4; ++j) {
    lo[j] = x[(size_t)(n0 + j) * 128 + lane];
    hi[j] = x[(size_t)(n0 + j) * 128 + 64 + lane];
  }
  *(float4*)&myrows[lane * 4] = make_float4(lo[0], lo[1], lo[2], lo[3]);
  *(float4*)&myrows[(64 + lane) * 4] = make_float4(hi[0], hi[1], hi[2], hi[3]);
  __asm__ volatile("s_waitcnt lgkmcnt(0)" ::: "memory");

  float acc[4] = {0.f, 0.f, 0.f, 0.f};
#pragma unroll 8
  for (int k = 0; k < 128; ++k) {
    float4 r = *(const float4*)&myrows[k * 4];
    float w = b2f(w1h[k * 64 + lane]);
    acc[0] += r.x * w;
    acc[1] += r.y * w;
    acc[2] += r.z * w;
    acc[3] += r.w * w;
  }
#pragma unroll
  for (int j = 0; j < 4; ++j) z[(size_t)(n0 + j) * 64 + lane] = f2b(acc[j]);
}

// ---------------- agg v4: precomputed CSR, paired-edge u32 gather ---------

template <bool HAS_NEXT>
__global__ __launch_bounds__(256) void agg_kernel(
    const u16* __restrict__ zin, const float* __restrict__ b1,
    const float* __restrict__ w2, const float* __restrict__ b2,
    const float* __restrict__ w1n, const float* __restrict__ eps, int li,
    const int* __restrict__ glofs, const int* __restrict__ glcol,
    u16* __restrict__ hout, u16* __restrict__ zn) {
  __shared__ u16 w2h[64 * 64];  // 8 KB
  __shared__ u16 w1nh[HAS_NEXT ? 64 * 64 : 2];
  __shared__ int lcol[LCAP];  // 9.2 KB
  __shared__ int lofs[65];
  __shared__ float rows[4][256];  // 4 KB
  const int tid = threadIdx.x;
  const int lane = tid & 63;
  const int wv = tid >> 6;
  const int sub = lane >> 5;       // 0: even edges, 1: odd edges
  const int fl = lane & 31;
  const int f = 2 * fl + sub;      // owned output/feature index
  const int blk = blockIdx.x;
  const int base = ((blk >> 1) << 7) + ((blk & 1) << 6);

  for (int i = tid; i < 64 * 64; i += 256) {
    w2h[i] = f2b(w2[i]);
    if (HAS_NEXT) w1nh[i] = f2b(w1n[i]);
  }
  if (tid < 65) lofs[tid] = glofs[blk * GOFS + tid];
  __syncthreads();
  const int L = lofs[64];
  {
    int4* ldst = (int4*)lcol;
    const int4* gsrc = (const int4*)(glcol + (size_t)blk * LCAP);
    for (int i = tid; i < (L >> 2); i += 256) ldst[i] = gsrc[i];
  }
  __syncthreads();

  const float e1 = 1.0f + eps[li];
  const float b1v = b1[f];
  const float b2v = b2[f];
  float* myrows = rows[wv];

#pragma unroll 1
  for (int pass = 0; pass < 4; ++pass) {
    const int ln0 = pass * 16 + wv * 4;
    float a[4];
#pragma unroll
    for (int j = 0; j < 4; ++j) {
      int ln = ln0 + j;
      int nn = base + ln;
      int sn = (nn < NNODES) ? nn : NNODES;
      int rs = lofs[ln], re = lofs[ln + 1];
      // 8 independent u32 loads = 16 edges per iteration
      float sa0 = 0.f, sa1 = 0.f, sa2 = 0.f, sa3 = 0.f;
      float sb0 = 0.f, sb1 = 0.f, sb2 = 0.f, sb3 = 0.f;
      for (int e = rs; e < re; e += 16) {
        int c0 = lcol[e + 0 + sub];
        int c1 = lcol[e + 2 + sub];
        int c2 = lcol[e + 4 + sub];
        int c3 = lcol[e + 6 + sub];
        int c4 = lcol[e + 8 + sub];
        int c5 = lcol[e + 10 + sub];
        int c6 = lcol[e + 12 + sub];
        int c7 = lcol[e + 14 + sub];
        u32 v0 = *(const u32*)&zin[(size_t)c0 * 64 + 2 * fl];
        u32 v1 = *(const u32*)&zin[(size_t)c1 * 64 + 2 * fl];
        u32 v2 = *(const u32*)&zin[(size_t)c2 * 64 + 2 * fl];
        u32 v3 = *(const u32*)&zin[(size_t)c3 * 64 + 2 * fl];
        u32 v4 = *(const u32*)&zin[(size_t)c4 * 64 + 2 * fl];
        u32 v5 = *(const u32*)&zin[(size_t)c5 * 64 + 2 * fl];
        u32 v6 = *(const u32*)&zin[(size_t)c6 * 64 + 2 * fl];
        u32 v7 = *(const u32*)&zin[(size_t)c7 * 64 + 2 * fl];
        sa0 += __uint_as_float(v0 << 16);
        sb0 += __uint_as_float(v0 & 0xffff0000u);
        sa1 += __uint_as_float(v1 << 16);
        sb1 += __uint_as_float(v1 & 0xffff0000u);
        sa2 += __uint_as_float(v2 << 16);
        sb2 += __uint_as_float(v2 & 0xffff0000u);
        sa3 += __uint_as_float(v3 << 16);
        sb3 += __uint_as_float(v3 & 0xffff0000u);
        sa0 += __uint_as_float(v4 << 16);
        sb0 += __uint_as_float(v4 & 0xffff0000u);
        sa1 += __uint_as_float(v5 << 16);
        sb1 += __uint_as_float(v5 & 0xffff0000u);
        sa2 += __uint_as_float(v6 << 16);
        sb2 += __uint_as_float(v6 & 0xffff0000u);
        sa3 += __uint_as_float(v7 << 16);
        sb3 += __uint_as_float(v7 & 0xffff0000u);
      }
      float sa = (sa0 + sa1) + (sa2 + sa3);  // feat 2fl, my half's edges
      float sb = (sb0 + sb1) + (sb2 + sb3);  // feat 2fl+1
      sa += __shfl_xor(sa, 32);              // combine halves
      sb += __shfl_xor(sb, 32);
      float sum = sub ? sb : sa;             // my feature f
      float self = b2f(zin[(size_t)sn * 64 + f]);
      a[j] = sum + e1 * self;
    }
#pragma unroll
    for (int j = 0; j < 4; ++j) a[j] = fmaxf(a[j] + b1v, 0.f);
    *(float4*)&myrows[f * 4] = make_float4(a[0], a[1], a[2], a[3]);
    __asm__ volatile("s_waitcnt lgkmcnt(0)" ::: "memory");

    float o0 = b2v, o1 = b2v, o2 = b2v, o3 = b2v;
#pragma unroll 8
    for (int k = 0; k < 64; ++k) {
      float4 r = *(const float4*)&myrows[k * 4];  // broadcast
      float w = b2f(w2h[k * 64 + f]);
      o0 += r.x * w;
      o1 += r.y * w;
      o2 += r.z * w;
      o3 += r.w * w;
    }
    o0 = fmaxf(o0, 0.f);
    o1 = fmaxf(o1, 0.f);
    o2 = fmaxf(o2, 0.f);
    o3 = fmaxf(o3, 0.f);
    int nn = base + ln0;
    if (nn + 0 < NNODES) hout[(size_t)(nn + 0) * 64 + f] = f2b(o0);
    if (nn + 1 < NNODES) hout[(size_t)(nn + 1) * 64 + f] = f2b(o1);
    if (nn + 2 < NNODES) hout[(size_t)(nn + 2) * 64 + f] = f2b(o2);
    if (nn + 3 < NNODES) hout[(size_t)(nn + 3) * 64 + f] = f2b(o3);

    if (HAS_NEXT) {
      __asm__ volatile("s_waitcnt lgkmcnt(0)" ::: "memory");
      *(float4*)&myrows[f * 4] = make_float4(o0, o1, o2, o3);
      __asm__ volatile("s_waitcnt lgkmcnt(0)" ::: "memory");
      float q0 = 0.f, q1 = 0.f, q2 = 0.f, q3 = 0.f;
#pragma unroll 8
      for (int k = 0; k < 64; ++k) {
        float4 r = *(const float4*)&myrows[k * 4];
        float w = b2f(w1nh[k * 64 + f]);
        q0 += r.x * w;
        q1 += r.y * w;
        q2 += r.z * w;
        q3 += r.w * w;
      }
      if (nn + 0 < NNODES) zn[(size_t)(nn + 0) * 64 + f] = f2b(q0);
      if (nn + 1 < NNODES) zn[(size_t)(nn + 1) * 64 + f] = f2b(q1);
      if (nn + 2 < NNODES) zn[(size_t)(nn + 2) * 64 + f] = f2b(q2);
      if (nn + 3 < NNODES) zn[(size_t)(nn + 3) * 64 + f] = f2b(q3);
    }
    __asm__ volatile("s_waitcnt lgkmcnt(0)" ::: "memory");
  }
}

// ---------------- Per-graph pooling (batch sorted, h bf16) ----------------

__device__ __forceinline__ int lower_bound(const int* __restrict__ a, int n,
                                           int v) {
  int lo = 0, hi = n;
  while (lo < hi) {
    int m = (lo + hi) >> 1;
    if (a[m] < v)
      lo = m + 1;
    else
      hi = m;
  }
  return lo;
}

__global__ __launch_bounds__(256) void pool_kernel(const u16* __restrict__ h,
                                                   const int* __restrict__ batch,
                                                   float* __restrict__ g,
                                                   int li) {
  int gi = blockIdx.x;
  int tid = threadIdx.x;
  int sub = tid >> 6, f = tid & 63;
  int s = lower_bound(batch, NNODES, gi);
  int e = lower_bound(batch, NNODES, gi + 1);
  float sum = 0.f, mx = -3.0e38f;
  for (int n = s + sub; n < e; n += 4) {
    float v = b2f(h[(size_t)n * 64 + f]);
    sum += v;
    mx = fmaxf(mx, v);
  }
  __shared__ float ssum[4][64];
  __shared__ float smax[4][64];
  ssum[sub][f] = sum;
  smax[sub][f] = mx;
  __syncthreads();
  if (tid < 64) {
    float S = ssum[0][f] + ssum[1][f] + ssum[2][f] + ssum[3][f];
    float M = fmaxf(fmaxf(smax[0][f], smax[1][f]), fmaxf(smax[2][f], smax[3][f]));
    int cnt = e - s;
    float mean = S / fmaxf((float)cnt, 1.0f);
    int base = gi * 576 + li * 64 + f;
    g[base] = mean;
    g[base + 192] = M;
    g[base + 384] = S;
  }
}

// ---------------- Head ----------------

__global__ __launch_bounds__(256) void head_kernel(
    const float* __restrict__ g, const float* __restrict__ fc1w,
    const float* __restrict__ fc1b, const float* __restrict__ fc2w,
    const float* __restrict__ fc2b, float* __restrict__ out) {
  __shared__ float gs[4 * 576];
  int tid = threadIdx.x;
  int g0 = blockIdx.x * 4;
  for (int i = tid; i < 4 * 576; i += 256) gs[i] = g[g0 * 576 + i];
  __syncthreads();
  int wv = tid >> 6, lane = tid & 63;
  int gi = g0 + wv;
  const float* grow = &gs[wv * 576];
  float acc = fc1b[lane];
#pragma unroll 8
  for (int k = 0; k < 576; ++k) acc += grow[k] * fc1w[k * 64 + lane];
  acc = fmaxf(acc, 0.f);
  float p0 = acc * fc2w[lane * 2 + 0];
  float p1 = acc * fc2w[lane * 2 + 1];
  for (int off = 32; off; off >>= 1) {
    p0 += __shfl_down(p0, off);
    p1 += __shfl_down(p1, off);
  }
  if (lane == 0) {
    out[gi * 2 + 0] = 1.f / (1.f + __expf(-(p0 + fc2b[0])));
    out[gi * 2 + 1] = 1.f / (1.f + __expf(-(p1 + fc2b[1])));
  }
}

// ---------------- launch ----------------

extern "C" void kernel_launch(void* const* d_in, const int* in_sizes, int n_in,
                              void* d_out, int out_size, void* d_ws,
                              size_t ws_size, hipStream_t stream) {
  const float* x = (const float*)d_in[0];
  const int* ei = (const int*)d_in[1];
  const int* src = ei;
  const int* dst = ei + NEDGES;
  const int* batch = (const int*)d_in[2];
  const float* lw1[3] = {(const float*)d_in[3], (const float*)d_in[7],
                         (const float*)d_in[11]};
  const float* lb1[3] = {(const float*)d_in[4], (const float*)d_in[8],
                         (const float*)d_in[12]};
  const float* lw2[3] = {(const float*)d_in[5], (const float*)d_in[9],
                         (const float*)d_in[13]};
  const float* lb2[3] = {(const float*)d_in[6], (const float*)d_in[10],
                         (const float*)d_in[14]};
  const float* eps = (const float*)d_in[15];
  const float* fc1w = (const float*)d_in[16];
  const float* fc1b = (const float*)d_in[17];
  const float* fc2w = (const float*)d_in[18];
  const float* fc2b = (const float*)d_in[19];
  float* out = (float*)d_out;

  char* p = (char*)d_ws;
  auto carve = [&](size_t bytes) {
    void* r = (void*)p;
    p += (bytes + 1023) & ~(size_t)1023;
    return r;
  };
  int* gcur = (int*)carve((NB + 4) * 4);
  int* st = (int*)carve((size_t)NB * BCAP * 4);
  int* glofs = (int*)carve((size_t)NBH * GOFS * 4);
  int* glcol = (int*)carve((size_t)NBH * LCAP * 4);
  u16* zA = (u16*)carve((size_t)(NNODES + 1) * 64 * 2);
  u16* zB = (u16*)carve((size_t)(NNODES + 1) * 64 * 2);
  u16* hA = (u16*)carve((size_t)NNODES * 64 * 2);
  float* g = (float*)carve((size_t)NGRAPHS * 576 * 4);

  init_kernel<<<4, 256, 0, stream>>>(gcur, zA, zB);
  bin_kernel<<<NCHUNKS, 512, 0, stream>>>(src, dst, gcur, st);
  csr_kernel<<<NBH, 256, 0, stream>>>(gcur, st, glofs, glcol);

  gemm128_kernel<<<3125, 512, 0, stream>>>(x, lw1[0], zA);

  agg_kernel<true><<<NBH, 256, 0, stream>>>(zA, lb1[0], lw2[0], lb2[0], lw1[1],
                                            eps, 0, glofs, glcol, hA, zB);
  pool_kernel<<<NGRAPHS, 256, 0, stream>>>(hA, batch, g, 0);

  agg_kernel<true><<<NBH, 256, 0, stream>>>(zB, lb1[1], lw2[1], lb2[1], lw1[2],
                                            eps, 1, glofs, glcol, hA, zA);
  pool_kernel<<<NGRAPHS, 256, 0, stream>>>(hA, batch, g, 1);

  agg_kernel<false><<<NBH, 256, 0, stream>>>(zA, lb1[2], lw2[2], lb2[2],
                                             (const float*)nullptr, eps, 2,
                                             glofs, glcol, hA, (u16*)nullptr);
  pool_kernel<<<NGRAPHS, 256, 0, stream>>>(hA, batch, g, 2);

  head_kernel<<<NGRAPHS / 4, 256, 0, stream>>>(g, fc1w, fc1b, fc2w, fc2b, out);
}

// Round 8
// 437.706 us; speedup vs baseline: 5.7081x; 1.0688x over previous
//
#include <hip/hip_runtime.h>
#include <math.h>

// GIN: agg commutes with first linear -> z = x@w1 precomputed (bf16).
// v5: MLPs on MFMA (mfma_f32_16x16x32_bf16). Agg: gather (paired-edge u32,
// precomputed CSR) -> H1 bf16 LDS tile -> MFMA h1@w2 -> H2 -> MFMA h@w1n.
// lcol aliases H1/H2 (dead after gather). gemm128 also MFMA.
// Layouts (verified, learn_hip m89/m91/m120): A[m=lane&15][k=quad*8+j],
// B[k=quad*8+j][n=lane&15], D col=lane&15 row=quad*4+reg.

#define NNODES 100000
#define NEDGES 1600000
#define NGRAPHS 512
#define NB 782       // staging buckets of 128 dst nodes
#define NBH 1564     // half-buckets (64 nodes) = agg/csr grid
#define BCAP 2560    // per-bucket staging capacity (mean 2046, sd 45)
#define LCAP 2304    // half-bucket padded CSR cap (mean ~1520, mult 16)
#define GOFS 72      // glofs row stride
#define CHUNK 4096
#define NCHUNKS 391  // ceil(1600000/4096)
#define HSTR 72      // H1/H2 row stride (u16), 144B = 9*16 -> 16B aligned
#define XSTR 136     // gemm x-tile row stride (u16), 272B = 17*16

typedef unsigned short u16;
typedef unsigned int u32;
typedef __attribute__((ext_vector_type(8))) short short8;
typedef __attribute__((ext_vector_type(4))) float f32x4;

__device__ __forceinline__ u16 f2b(float f) {
  union { float f; unsigned u; } v;
  v.f = f;
  unsigned r = v.u + 0x7FFF + ((v.u >> 16) & 1);  // RN-even
  return (u16)(r >> 16);
}
__device__ __forceinline__ float b2f(u16 h) {
  union { unsigned u; float f; } v;
  v.u = ((unsigned)h) << 16;
  return v.f;
}

// ---------------- init: gcur + zero rows of zA/zB ----------------

__global__ __launch_bounds__(256) void init_kernel(int* __restrict__ gcur,
                                                   u16* __restrict__ zA,
                                                   u16* __restrict__ zB) {
  int i = blockIdx.x * 256 + threadIdx.x;
  if (i < NB) gcur[i] = i * BCAP;
  if (blockIdx.x == 3) {
    int t = threadIdx.x;
    if (t < 64) zA[(size_t)NNODES * 64 + t] = 0;
    else if (t < 128) zB[(size_t)NNODES * 64 + (t - 64)] = 0;
  }
}

// ---------------- binned scatter (128-node buckets) ----------------

__global__ __launch_bounds__(512) void bin_kernel(const int* __restrict__ src,
                                                  const int* __restrict__ dst,
                                                  int* __restrict__ gcur,
                                                  int* __restrict__ st) {
  __shared__ int hist[NB];
  __shared__ int lofs[NB + 1];
  __shared__ int lcur[NB];
  __shared__ int gbase[NB];
  __shared__ int sd[1024];
  __shared__ int staged[CHUNK];
  __shared__ u16 stb[CHUNK];
  const int t = threadIdx.x;
  const int e0 = blockIdx.x * CHUNK;
  const int n = min(CHUNK, NEDGES - e0);

  for (int i = t; i < NB; i += 512) hist[i] = 0;
  __syncthreads();

  int pk[8];
  int bk[8];
#pragma unroll
  for (int k = 0; k < 8; ++k) {
    int i = t + k * 512;
    if (i < n) {
      int s = src[e0 + i];
      int d = dst[e0 + i];
      int b = d >> 7;
      pk[k] = (s << 7) | (d & 127);
      bk[k] = b;
      atomicAdd(&hist[b], 1);
    } else {
      bk[k] = -1;
    }
  }
  __syncthreads();

  sd[t] = (t < NB) ? hist[t] : 0;
  sd[t + 512] = (t + 512 < NB) ? hist[t + 512] : 0;
  __syncthreads();
  for (int off = 1; off < 1024; off <<= 1) {
    int v0 = (t >= off) ? sd[t - off] : 0;
    int v1 = (t + 512 >= off) ? sd[t + 512 - off] : 0;
    __syncthreads();
    sd[t] += v0;
    sd[t + 512] += v1;
    __syncthreads();
  }
  if (t == 0) lofs[0] = 0;
  for (int i = t; i < NB; i += 512) {
    int inc = sd[i];
    int c = hist[i];
    lofs[i + 1] = inc;
    lcur[i] = inc - c;
    gbase[i] = c ? atomicAdd(&gcur[i], c) : 0;
  }
  __syncthreads();

#pragma unroll
  for (int k = 0; k < 8; ++k) {
    if (bk[k] >= 0) {
      int r = atomicAdd(&lcur[bk[k]], 1);
      staged[r] = pk[k];
      stb[r] = (u16)bk[k];
    }
  }
  __syncthreads();

  for (int i = t; i < n; i += 512) {
    int b = stb[i];
    st[gbase[b] + (i - lofs[b])] = staged[i];
  }
}

// ---------------- CSR build (ONCE): half-bucket -> global lofs/lcol -------

__global__ __launch_bounds__(256) void csr_kernel(const int* __restrict__ gcur,
                                                  const int* __restrict__ st,
                                                  int* __restrict__ glofs,
                                                  int* __restrict__ glcol) {
  __shared__ int lcol[LCAP];
  __shared__ int lhist[64];
  __shared__ int lofs[65];
  __shared__ int lcur[64];
  __shared__ int ssc[64];
  const int tid = threadIdx.x;
  const int blk = blockIdx.x;
  const int bkt = blk >> 1;
  const int half = blk & 1;
  const int ofs = bkt * BCAP;
  const int cnt = min(gcur[bkt] - ofs, BCAP);

  if (tid < 64) lhist[tid] = 0;
  __syncthreads();
  for (int i = tid; i < cnt; i += 256) {
    int d7 = st[ofs + i] & 127;
    if ((d7 >> 6) == half) atomicAdd(&lhist[d7 & 63], 1);
  }
  __syncthreads();
  if (tid < 64) ssc[tid] = (lhist[tid] + 15) & ~15;  // pad to mult-16
  __syncthreads();
  for (int off = 1; off < 64; off <<= 1) {
    int v = (tid < 64 && tid >= off) ? ssc[tid - off] : 0;
    __syncthreads();
    if (tid < 64) ssc[tid] += v;
    __syncthreads();
  }
  if (tid < 64) {
    lofs[tid + 1] = ssc[tid];
    lcur[tid] = ssc[tid] - ((lhist[tid] + 15) & ~15);
  }
  if (tid == 0) lofs[0] = 0;
  __syncthreads();
  for (int i = tid; i < cnt; i += 256) {
    int p = st[ofs + i];
    int d7 = p & 127;
    if ((d7 >> 6) == half) {
      int r = atomicAdd(&lcur[d7 & 63], 1);
      if (r < LCAP) lcol[r] = p >> 7;
    }
  }
  __syncthreads();
  if (tid < 64) {
    int re = min(lofs[tid + 1], LCAP);
    for (int r = lcur[tid]; r < re; ++r) lcol[r] = NNODES;  // sentinel
  }
  __syncthreads();
  if (tid < 65) glofs[blk * GOFS + tid] = min(lofs[tid], LCAP);
  int L = min(lofs[64], LCAP);
  int4* gdst = (int4*)(glcol + (size_t)blk * LCAP);
  const int4* lsrc = (const int4*)lcol;
  for (int i = tid; i < (L >> 2); i += 256) gdst[i] = lsrc[i];
}

// ---------------- GEMM (MFMA): z = x(Nx128) @ w1(128x64), z bf16 ----------

__global__ __launch_bounds__(256) void gemm128_kernel(
    const float* __restrict__ x, const float* __restrict__ w1,
    u16* __restrict__ z) {
  __shared__ u16 w1h[128 * 64];    // natural [k][of], 16 KB
  __shared__ u16 Xt[64 * XSTR];    // bf16 x-tile, 17 KB; reused as z-tile
  const int tid = threadIdx.x;
  const int base = blockIdx.x * 64;
  for (int i = tid; i < 128 * 64; i += 256) w1h[i] = f2b(w1[i]);
  for (int i = tid; i < 2048; i += 256) {  // 64 rows x 32 float4
    int n = i >> 5, c4 = i & 31;
    int nn = base + n;
    float4 v = make_float4(0.f, 0.f, 0.f, 0.f);
    if (nn < NNODES) v = *(const float4*)&x[(size_t)nn * 128 + 4 * c4];
    u32 p0 = (u32)f2b(v.x) | ((u32)f2b(v.y) << 16);
    u32 p1 = (u32)f2b(v.z) | ((u32)f2b(v.w) << 16);
    *(u32*)&Xt[n * XSTR + 4 * c4] = p0;
    *(u32*)&Xt[n * XSTR + 4 * c4 + 2] = p1;
  }
  __syncthreads();
  const int lane = tid & 63;
  const int wv = tid >> 6;
  const int mrow = lane & 15;
  const int quad = lane >> 4;
  f32x4 accs[4];
#pragma unroll
  for (int nt = 0; nt < 4; ++nt) {
    f32x4 acc = {0.f, 0.f, 0.f, 0.f};
    int ofb = nt * 16 + mrow;
#pragma unroll
    for (int ks = 0; ks < 4; ++ks) {
      short8 afr = *(const short8*)&Xt[(wv * 16 + mrow) * XSTR + ks * 32 + quad * 8];
      short8 bfr;
#pragma unroll
      for (int jj = 0; jj < 8; ++jj)
        bfr[jj] = (short)w1h[(ks * 32 + quad * 8 + jj) * 64 + ofb];
      acc = __builtin_amdgcn_mfma_f32_16x16x32_bf16(afr, bfr, acc, 0, 0, 0);
    }
    accs[nt] = acc;
  }
  __syncthreads();  // Xt dead; reuse as z-tile (stride HSTR)
  u16* Zt = Xt;
#pragma unroll
  for (int nt = 0; nt < 4; ++nt)
#pragma unroll
    for (int r = 0; r < 4; ++r)
      Zt[(wv * 16 + quad * 4 + r) * HSTR + nt * 16 + mrow] = f2b(accs[nt][r]);
  __syncthreads();
  for (int i = tid; i < 2048; i += 256) {
    int n = i >> 5, kk = i & 31;
    int nn = base + n;
    if (nn < NNODES) {
      u32 w = (u32)Zt[n * HSTR + 2 * kk] | ((u32)Zt[n * HSTR + 2 * kk + 1] << 16);
      *(u32*)&z[(size_t)nn * 64 + 2 * kk] = w;
    }
  }
}

// ---------------- agg v5: CSR gather + MFMA MLP ----------------

template <bool HAS_NEXT>
__global__ __launch_bounds__(256) void agg_kernel(
    const u16* __restrict__ zin, const float* __restrict__ b1,
    const float* __restrict__ w2, const float* __restrict__ b2,
    const float* __restrict__ w1n, const float* __restrict__ eps, int li,
    const int* __restrict__ glofs, const int* __restrict__ glcol,
    u16* __restrict__ hout, u16* __restrict__ zn) {
  __shared__ u16 w2h[64 * 64];  // natural [k][of], 8 KB
  __shared__ u16 w1nh[HAS_NEXT ? 64 * 64 : 8];
  __shared__ float b2s[64];
  __shared__ int lofs[65];
  __shared__ char scratch[2 * 64 * HSTR * 2];  // 18432 B
  int* lcol = (int*)scratch;                   // LCAP*4 = 9216 B (aliased)
  u16* H1 = (u16*)scratch;                     // 64 x HSTR
  u16* H2 = (u16*)(scratch + 64 * HSTR * 2);   // 64 x HSTR
  const int tid = threadIdx.x;
  const int lane = tid & 63;
  const int wv = tid >> 6;
  const int sub = lane >> 5;
  const int fl = lane & 31;
  const int f = 2 * fl + sub;  // owned (permuted) feature
  const int blk = blockIdx.x;
  const int base = ((blk >> 1) << 7) + ((blk & 1) << 6);

  for (int i = tid; i < 64 * 64; i += 256) {
    w2h[i] = f2b(w2[i]);
    if (HAS_NEXT) w1nh[i] = f2b(w1n[i]);
  }
  if (tid < 64) b2s[tid] = b2[tid];
  if (tid < 65) lofs[tid] = glofs[blk * GOFS + tid];
  __syncthreads();
  const int L = lofs[64];
  {
    int4* ldst = (int4*)lcol;
    const int4* gsrc = (const int4*)(glcol + (size_t)blk * LCAP);
    for (int i = tid; i < (L >> 2); i += 256) ldst[i] = gsrc[i];
  }
  __syncthreads();

  const float e1 = 1.0f + eps[li];
  const float b1v = b1[f];
  const int n0 = wv * 16;

  float av[16];
#pragma unroll 1
  for (int j = 0; j < 16; ++j) {
    int ln = n0 + j;
    int nn = base + ln;
    int sn = (nn < NNODES) ? nn : NNODES;
    int rs = lofs[ln], re = lofs[ln + 1];
    float sa0 = 0.f, sa1 = 0.f, sa2 = 0.f, sa3 = 0.f;
    float sb0 = 0.f, sb1 = 0.f, sb2 = 0.f, sb3 = 0.f;
    for (int e = rs; e < re; e += 16) {
      int c0 = lcol[e + 0 + sub];
      int c1 = lcol[e + 2 + sub];
      int c2 = lcol[e + 4 + sub];
      int c3 = lcol[e + 6 + sub];
      int c4 = lcol[e + 8 + sub];
      int c5 = lcol[e + 10 + sub];
      int c6 = lcol[e + 12 + sub];
      int c7 = lcol[e + 14 + sub];
      u32 v0 = *(const u32*)&zin[(size_t)c0 * 64 + 2 * fl];
      u32 v1 = *(const u32*)&zin[(size_t)c1 * 64 + 2 * fl];
      u32 v2 = *(const u32*)&zin[(size_t)c2 * 64 + 2 * fl];
      u32 v3 = *(const u32*)&zin[(size_t)c3 * 64 + 2 * fl];
      u32 v4 = *(const u32*)&zin[(size_t)c4 * 64 + 2 * fl];
      u32 v5 = *(const u32*)&zin[(size_t)c5 * 64 + 2 * fl];
      u32 v6 = *(const u32*)&zin[(size_t)c6 * 64 + 2 * fl];
      u32 v7 = *(const u32*)&zin[(size_t)c7 * 64 + 2 * fl];
      sa0 += __uint_as_float(v0 << 16);
      sb0 += __uint_as_float(v0 & 0xffff0000u);
      sa1 += __uint_as_float(v1 << 16);
      sb1 += __uint_as_float(v1 & 0xffff0000u);
      sa2 += __uint_as_float(v2 << 16);
      sb2 += __uint_as_float(v2 & 0xffff0000u);
      sa3 += __uint_as_float(v3 << 16);
      sb3 += __uint_as_float(v3 & 0xffff0000u);
      sa0 += __uint_as_float(v4 << 16);
      sb0 += __uint_as_float(v4 & 0xffff0000u);
      sa1 += __uint_as_float(v5 << 16);
      sb1 += __uint_as_float(v5 & 0xffff0000u);
      sa2 += __uint_as_float(v6 << 16);
      sb2 += __uint_as_float(v6 & 0xffff0000u);
      sa3 += __uint_as_float(v7 << 16);
      sb3 += __uint_as_float(v7 & 0xffff0000u);
    }
    float sa = (sa0 + sa1) + (sa2 + sa3);
    float sb = (sb0 + sb1) + (sb2 + sb3);
    sa += __shfl_xor(sa, 32);
    sb += __shfl_xor(sb, 32);
    float sum = sub ? sb : sa;
    float self = b2f(zin[(size_t)sn * 64 + f]);
    av[j] = fmaxf(sum + e1 * self + b1v, 0.f);  // h1
  }
  __syncthreads();  // lcol dead -> H1/H2 live
#pragma unroll
  for (int j = 0; j < 16; ++j) H1[(n0 + j) * HSTR + f] = f2b(av[j]);
  __syncthreads();

  const int mrow = lane & 15;
  const int quad = lane >> 4;
  // matmul1: H2 = relu(H1 @ w2 + b2)
#pragma unroll
  for (int nt = 0; nt < 4; ++nt) {
    f32x4 acc = {0.f, 0.f, 0.f, 0.f};
    int ofb = nt * 16 + mrow;
#pragma unroll
    for (int ks = 0; ks < 2; ++ks) {
      short8 afr = *(const short8*)&H1[(wv * 16 + mrow) * HSTR + ks * 32 + quad * 8];
      short8 bfr;
#pragma unroll
      for (int jj = 0; jj < 8; ++jj)
        bfr[jj] = (short)w2h[(ks * 32 + quad * 8 + jj) * 64 + ofb];
      acc = __builtin_amdgcn_mfma_f32_16x16x32_bf16(afr, bfr, acc, 0, 0, 0);
    }
    float bb = b2s[ofb];
#pragma unroll
    for (int r = 0; r < 4; ++r)
      H2[(wv * 16 + quad * 4 + r) * HSTR + ofb] = f2b(fmaxf(acc[r] + bb, 0.f));
  }
  __syncthreads();
  // coalesced hout store from H2
  for (int i = tid; i < 2048; i += 256) {
    int n = i >> 5, kk = i & 31;
    int nn = base + n;
    if (nn < NNODES) {
      u32 w = (u32)H2[n * HSTR + 2 * kk] | ((u32)H2[n * HSTR + 2 * kk + 1] << 16);
      *(u32*)&hout[(size_t)nn * 64 + 2 * kk] = w;
    }
  }

  if (HAS_NEXT) {
    // matmul2: H1 = H2 @ w1n (no relu), then coalesced zn store
#pragma unroll
    for (int nt = 0; nt < 4; ++nt) {
      f32x4 acc = {0.f, 0.f, 0.f, 0.f};
      int ofb = nt * 16 + mrow;
#pragma unroll
      for (int ks = 0; ks < 2; ++ks) {
        short8 afr = *(const short8*)&H2[(wv * 16 + mrow) * HSTR + ks * 32 + quad * 8];
        short8 bfr;
#pragma unroll
        for (int jj = 0; jj < 8; ++jj)
          bfr[jj] = (short)w1nh[(ks * 32 + quad * 8 + jj) * 64 + ofb];
        acc = __builtin_amdgcn_mfma_f32_16x16x32_bf16(afr, bfr, acc, 0, 0, 0);
      }
#pragma unroll
      for (int r = 0; r < 4; ++r)
        H1[(wv * 16 + quad * 4 + r) * HSTR + ofb] = f2b(acc[r]);
    }
    __syncthreads();
    for (int i = tid; i < 2048; i += 256) {
      int n = i >> 5, kk = i & 31;
      int nn = base + n;
      if (nn < NNODES) {
        u32 w = (u32)H1[n * HSTR + 2 * kk] | ((u32)H1[n * HSTR + 2 * kk + 1] << 16);
        *(u32*)&zn[(size_t)nn * 64 + 2 * kk] = w;
      }
    }
  }
}

// ---------------- Per-graph pooling (batch sorted, h bf16) ----------------

__device__ __forceinline__ int lower_bound(const int* __restrict__ a, int n,
                                           int v) {
  int lo = 0, hi = n;
  while (lo < hi) {
    int m = (lo + hi) >> 1;
    if (a[m] < v)
      lo = m + 1;
    else
      hi = m;
  }
  return lo;
}

__global__ __launch_bounds__(256) void pool_kernel(const u16* __restrict__ h,
                                                   const int* __restrict__ batch,
                                                   float* __restrict__ g,
                                                   int li) {
  int gi = blockIdx.x;
  int tid = threadIdx.x;
  int sub = tid >> 6, f = tid & 63;
  int s = lower_bound(batch, NNODES, gi);
  int e = lower_bound(batch, NNODES, gi + 1);
  float sum = 0.f, mx = -3.0e38f;
  for (int n = s + sub; n < e; n += 4) {
    float v = b2f(h[(size_t)n * 64 + f]);
    sum += v;
    mx = fmaxf(mx, v);
  }
  __shared__ float ssum[4][64];
  __shared__ float smax[4][64];
  ssum[sub][f] = sum;
  smax[sub][f] = mx;
  __syncthreads();
  if (tid < 64) {
    float S = ssum[0][f] + ssum[1][f] + ssum[2][f] + ssum[3][f];
    float M = fmaxf(fmaxf(smax[0][f], smax[1][f]), fmaxf(smax[2][f], smax[3][f]));
    int cnt = e - s;
    float mean = S / fmaxf((float)cnt, 1.0f);
    int base = gi * 576 + li * 64 + f;
    g[base] = mean;
    g[base + 192] = M;
    g[base + 384] = S;
  }
}

// ---------------- Head ----------------

__global__ __launch_bounds__(256) void head_kernel(
    const float* __restrict__ g, const float* __restrict__ fc1w,
    const float* __restrict__ fc1b, const float* __restrict__ fc2w,
    const float* __restrict__ fc2b, float* __restrict__ out) {
  __shared__ float gs[4 * 576];
  int tid = threadIdx.x;
  int g0 = blockIdx.x * 4;
  for (int i = tid; i < 4 * 576; i += 256) gs[i] = g[g0 * 576 + i];
  __syncthreads();
  int wv = tid >> 6, lane = tid & 63;
  int gi = g0 + wv;
  const float* grow = &gs[wv * 576];
  float acc = fc1b[lane];
#pragma unroll 8
  for (int k = 0; k < 576; ++k) acc += grow[k] * fc1w[k * 64 + lane];
  acc = fmaxf(acc, 0.f);
  float p0 = acc * fc2w[lane * 2 + 0];
  float p1 = acc * fc2w[lane * 2 + 1];
  for (int off = 32; off; off >>= 1) {
    p0 += __shfl_down(p0, off);
    p1 += __shfl_down(p1, off);
  }
  if (lane == 0) {
    out[gi * 2 + 0] = 1.f / (1.f + __expf(-(p0 + fc2b[0])));
    out[gi * 2 + 1] = 1.f / (1.f + __expf(-(p1 + fc2b[1])));
  }
}

// ---------------- launch ----------------

extern "C" void kernel_launch(void* const* d_in, const int* in_sizes, int n_in,
                              void* d_out, int out_size, void* d_ws,
                              size_t ws_size, hipStream_t stream) {
  const float* x = (const float*)d_in[0];
  const int* ei = (const int*)d_in[1];
  const int* src = ei;
  const int* dst = ei + NEDGES;
  const int* batch = (const int*)d_in[2];
  const float* lw1[3] = {(const float*)d_in[3], (const float*)d_in[7],
                         (const float*)d_in[11]};
  const float* lb1[3] = {(const float*)d_in[4], (const float*)d_in[8],
                         (const float*)d_in[12]};
  const float* lw2[3] = {(const float*)d_in[5], (const float*)d_in[9],
                         (const float*)d_in[13]};
  const float* lb2[3] = {(const float*)d_in[6], (const float*)d_in[10],
                         (const float*)d_in[14]};
  const float* eps = (const float*)d_in[15];
  const float* fc1w = (const float*)d_in[16];
  const float* fc1b = (const float*)d_in[17];
  const float* fc2w = (const float*)d_in[18];
  const float* fc2b = (const float*)d_in[19];
  float* out = (float*)d_out;

  char* p = (char*)d_ws;
  auto carve = [&](size_t bytes) {
    void* r = (void*)p;
    p += (bytes + 1023) & ~(size_t)1023;
    return r;
  };
  int* gcur = (int*)carve((NB + 4) * 4);
  int* st = (int*)carve((size_t)NB * BCAP * 4);
  int* glofs = (int*)carve((size_t)NBH * GOFS * 4);
  int* glcol = (int*)carve((size_t)NBH * LCAP * 4);
  u16* zA = (u16*)carve((size_t)(NNODES + 1) * 64 * 2);
  u16* zB = (u16*)carve((size_t)(NNODES + 1) * 64 * 2);
  u16* hA = (u16*)carve((size_t)NNODES * 64 * 2);
  float* g = (float*)carve((size_t)NGRAPHS * 576 * 4);

  init_kernel<<<4, 256, 0, stream>>>(gcur, zA, zB);
  bin_kernel<<<NCHUNKS, 512, 0, stream>>>(src, dst, gcur, st);
  csr_kernel<<<NBH, 256, 0, stream>>>(gcur, st, glofs, glcol);

  gemm128_kernel<<<1563, 256, 0, stream>>>(x, lw1[0], zA);

  agg_kernel<true><<<NBH, 256, 0, stream>>>(zA, lb1[0], lw2[0], lb2[0], lw1[1],
                                            eps, 0, glofs, glcol, hA, zB);
  pool_kernel<<<NGRAPHS, 256, 0, stream>>>(hA, batch, g, 0);

  agg_kernel<true><<<NBH, 256, 0, stream>>>(zB, lb1[1], lw2[1], lb2[1], lw1[2],
                                            eps, 1, glofs, glcol, hA, zA);
  pool_kernel<<<NGRAPHS, 256, 0, stream>>>(hA, batch, g, 1);

  agg_kernel<false><<<NBH, 256, 0, stream>>>(zA, lb1[2], lw2[2], lb2[2],
                                             (const float*)nullptr, eps, 2,
                                             glofs, glcol, hA, (u16*)nullptr);
  pool_kernel<<<NGRAPHS, 256, 0, stream>>>(hA, batch, g, 2);

  head_kernel<<<NGRAPHS / 4, 256, 0, stream>>>(g, fc1w, fc1b, fc2w, fc2b, out);
}

// Round 9
// 415.111 us; speedup vs baseline: 6.0188x; 1.0544x over previous
//
#include <hip/hip_runtime.h>
#include <math.h>

// GIN v6: z = x@w1 precomputed (bf16, MFMA). Per layer agg:
//   gather (paired-edge u32, precomputed CSR) -> H1 -> MFMA h1@w2 -> H2
//   -> fused pooling (sum/max atomics; h never hits global!) -> MFMA h@w1n -> zn.
// Weights pre-swizzled into per-lane MFMA B-fragment order (prep_kernel) ->
// single conflict-floor ds_read_b128 per fragment (fixes R8's 2M conflicts).
// w1next frags staged into dead H1 region -> LDS 27.5KB -> 5 blocks/CU.

#define NNODES 100000
#define NEDGES 1600000
#define NGRAPHS 512
#define NB 782
#define NBH 1564
#define BCAP 2560
#define LCAP 2304
#define GOFS 72
#define CHUNK 4096
#define NCHUNKS 391
#define HSTR 72   // H1/H2 row stride (u16): 144B, 36 dwords = 4 mod 32
#define XSTR 136  // gemm x-tile row stride (u16)

typedef unsigned short u16;
typedef unsigned int u32;
typedef __attribute__((ext_vector_type(8))) short short8;
typedef __attribute__((ext_vector_type(4))) float f32x4;

__device__ __forceinline__ u16 f2b(float f) {
  union { float f; unsigned u; } v;
  v.f = f;
  unsigned r = v.u + 0x7FFF + ((v.u >> 16) & 1);
  return (u16)(r >> 16);
}
__device__ __forceinline__ float b2f(u16 h) {
  union { unsigned u; float f; } v;
  v.u = ((unsigned)h) << 16;
  return v.f;
}
#define LDS_FENCE() __asm__ volatile("s_waitcnt lgkmcnt(0)" ::: "memory")

// ---------------- init ----------------

__global__ __launch_bounds__(256) void init_kernel(int* __restrict__ gcur,
                                                   u16* __restrict__ zA,
                                                   u16* __restrict__ zB) {
  int i = blockIdx.x * 256 + threadIdx.x;
  if (i < NB) gcur[i] = i * BCAP;
  if (blockIdx.x == 3) {
    int t = threadIdx.x;
    if (t < 64) zA[(size_t)NNODES * 64 + t] = 0;
    else if (t < 128) zB[(size_t)NNODES * 64 + (t - 64)] = 0;
  }
}

// ---------------- per-graph node counts ----------------

__global__ __launch_bounds__(1024) void cnt_kernel(const int* __restrict__ batch,
                                                   int* __restrict__ gcnt) {
  int i = blockIdx.x * 1024 + threadIdx.x;
  if (i < NNODES) atomicAdd(&gcnt[batch[i]], 1);
}

// ---------------- weight pre-swizzle to MFMA B-fragment order -------------
// frag layout: dst[((nt*KS + ks)*64 + lane)*8 + jj] = w[(ks*32+quad*8+jj)*F + nt*16+mrow]

__global__ __launch_bounds__(256) void prep_kernel(
    const float* __restrict__ w1g, const float* __restrict__ w2a,
    const float* __restrict__ w2b, const float* __restrict__ w2c,
    const float* __restrict__ w1b, const float* __restrict__ w1c,
    u16* __restrict__ w1f, u16* __restrict__ w2fa, u16* __restrict__ w2fb,
    u16* __restrict__ w2fc, u16* __restrict__ w1nfb, u16* __restrict__ w1nfc) {
  int blk = blockIdx.x, tid = threadIdx.x;
  if (blk == 0) {  // 128x64
    for (int i = tid; i < 8192; i += 256) {
      int jj = i & 7, lane = (i >> 3) & 63, c = i >> 9;
      int nt = c >> 2, ks = c & 3;
      int mrow = lane & 15, quad = lane >> 4;
      w1f[i] = f2b(w1g[(ks * 32 + quad * 8 + jj) * 64 + nt * 16 + mrow]);
    }
  } else {  // 64x64
    const float* s = (blk == 1) ? w2a : (blk == 2) ? w2b : (blk == 3) ? w2c
                    : (blk == 4) ? w1b : w1c;
    u16* d = (blk == 1) ? w2fa : (blk == 2) ? w2fb : (blk == 3) ? w2fc
             : (blk == 4) ? w1nfb : w1nfc;
    for (int i = tid; i < 4096; i += 256) {
      int jj = i & 7, lane = (i >> 3) & 63, c = i >> 9;
      int nt = c >> 1, ks = c & 1;
      int mrow = lane & 15, quad = lane >> 4;
      d[i] = f2b(s[(ks * 32 + quad * 8 + jj) * 64 + nt * 16 + mrow]);
    }
  }
}

// ---------------- binned scatter ----------------

__global__ __launch_bounds__(512) void bin_kernel(const int* __restrict__ src,
                                                  const int* __restrict__ dst,
                                                  int* __restrict__ gcur,
                                                  int* __restrict__ st) {
  __shared__ int hist[NB];
  __shared__ int lofs[NB + 1];
  __shared__ int lcur[NB];
  __shared__ int gbase[NB];
  __shared__ int sd[1024];
  __shared__ int staged[CHUNK];
  __shared__ u16 stb[CHUNK];
  const int t = threadIdx.x;
  const int e0 = blockIdx.x * CHUNK;
  const int n = min(CHUNK, NEDGES - e0);

  for (int i = t; i < NB; i += 512) hist[i] = 0;
  __syncthreads();

  int pk[8];
  int bk[8];
#pragma unroll
  for (int k = 0; k < 8; ++k) {
    int i = t + k * 512;
    if (i < n) {
      int s = src[e0 + i];
      int d = dst[e0 + i];
      int b = d >> 7;
      pk[k] = (s << 7) | (d & 127);
      bk[k] = b;
      atomicAdd(&hist[b], 1);
    } else {
      bk[k] = -1;
    }
  }
  __syncthreads();

  sd[t] = (t < NB) ? hist[t] : 0;
  sd[t + 512] = (t + 512 < NB) ? hist[t + 512] : 0;
  __syncthreads();
  for (int off = 1; off < 1024; off <<= 1) {
    int v0 = (t >= off) ? sd[t - off] : 0;
    int v1 = (t + 512 >= off) ? sd[t + 512 - off] : 0;
    __syncthreads();
    sd[t] += v0;
    sd[t + 512] += v1;
    __syncthreads();
  }
  if (t == 0) lofs[0] = 0;
  for (int i = t; i < NB; i += 512) {
    int inc = sd[i];
    int c = hist[i];
    lofs[i + 1] = inc;
    lcur[i] = inc - c;
    gbase[i] = c ? atomicAdd(&gcur[i], c) : 0;
  }
  __syncthreads();

#pragma unroll
  for (int k = 0; k < 8; ++k) {
    if (bk[k] >= 0) {
      int r = atomicAdd(&lcur[bk[k]], 1);
      staged[r] = pk[k];
      stb[r] = (u16)bk[k];
    }
  }
  __syncthreads();

  for (int i = t; i < n; i += 512) {
    int b = stb[i];
    st[gbase[b] + (i - lofs[b])] = staged[i];
  }
}

// ---------------- CSR build (once) ----------------

__global__ __launch_bounds__(256) void csr_kernel(const int* __restrict__ gcur,
                                                  const int* __restrict__ st,
                                                  int* __restrict__ glofs,
                                                  int* __restrict__ glcol) {
  __shared__ int lcol[LCAP];
  __shared__ int lhist[64];
  __shared__ int lofs[65];
  __shared__ int lcur[64];
  __shared__ int ssc[64];
  const int tid = threadIdx.x;
  const int blk = blockIdx.x;
  const int bkt = blk >> 1;
  const int half = blk & 1;
  const int ofs = bkt * BCAP;
  const int cnt = min(gcur[bkt] - ofs, BCAP);

  if (tid < 64) lhist[tid] = 0;
  __syncthreads();
  for (int i = tid; i < cnt; i += 256) {
    int d7 = st[ofs + i] & 127;
    if ((d7 >> 6) == half) atomicAdd(&lhist[d7 & 63], 1);
  }
  __syncthreads();
  if (tid < 64) ssc[tid] = (lhist[tid] + 15) & ~15;
  __syncthreads();
  for (int off = 1; off < 64; off <<= 1) {
    int v = (tid < 64 && tid >= off) ? ssc[tid - off] : 0;
    __syncthreads();
    if (tid < 64) ssc[tid] += v;
    __syncthreads();
  }
  if (tid < 64) {
    lofs[tid + 1] = ssc[tid];
    lcur[tid] = ssc[tid] - ((lhist[tid] + 15) & ~15);
  }
  if (tid == 0) lofs[0] = 0;
  __syncthreads();
  for (int i = tid; i < cnt; i += 256) {
    int p = st[ofs + i];
    int d7 = p & 127;
    if ((d7 >> 6) == half) {
      int r = atomicAdd(&lcur[d7 & 63], 1);
      if (r < LCAP) lcol[r] = p >> 7;
    }
  }
  __syncthreads();
  if (tid < 64) {
    int re = min(lofs[tid + 1], LCAP);
    for (int r = lcur[tid]; r < re; ++r) lcol[r] = NNODES;
  }
  __syncthreads();
  if (tid < 65) glofs[blk * GOFS + tid] = min(lofs[tid], LCAP);
  int L = min(lofs[64], LCAP);
  int4* gdst = (int4*)(glcol + (size_t)blk * LCAP);
  const int4* lsrc = (const int4*)lcol;
  for (int i = tid; i < (L >> 2); i += 256) gdst[i] = lsrc[i];
}

// ---------------- GEMM (MFMA): z = x(Nx128) @ w1, z bf16 ----------------

__global__ __launch_bounds__(256) void gemm128_kernel(
    const float* __restrict__ x, const u16* __restrict__ w1f,
    u16* __restrict__ z) {
  __shared__ u16 w1h[128 * 64];  // fragment order, 16 KB
  __shared__ u16 Xt[64 * XSTR];  // 17 KB; reused as z-tile
  const int tid = threadIdx.x;
  const int base = blockIdx.x * 64;
  for (int i = tid; i < 1024; i += 256) ((int4*)w1h)[i] = ((const int4*)w1f)[i];
  for (int i = tid; i < 2048; i += 256) {
    int n = i >> 5, c4 = i & 31;
    int nn = base + n;
    float4 v = make_float4(0.f, 0.f, 0.f, 0.f);
    if (nn < NNODES) v = *(const float4*)&x[(size_t)nn * 128 + 4 * c4];
    u32 p0 = (u32)f2b(v.x) | ((u32)f2b(v.y) << 16);
    u32 p1 = (u32)f2b(v.z) | ((u32)f2b(v.w) << 16);
    *(u32*)&Xt[n * XSTR + 4 * c4] = p0;
    *(u32*)&Xt[n * XSTR + 4 * c4 + 2] = p1;
  }
  __syncthreads();
  const int lane = tid & 63;
  const int wv = tid >> 6;
  const int mrow = lane & 15;
  const int quad = lane >> 4;
  f32x4 accs[4];
#pragma unroll
  for (int nt = 0; nt < 4; ++nt) {
    f32x4 acc = {0.f, 0.f, 0.f, 0.f};
#pragma unroll
    for (int ks = 0; ks < 4; ++ks) {
      short8 afr = *(const short8*)&Xt[(wv * 16 + mrow) * XSTR + ks * 32 + quad * 8];
      short8 bfr = *(const short8*)&w1h[((nt * 4 + ks) * 64 + lane) * 8];
      acc = __builtin_amdgcn_mfma_f32_16x16x32_bf16(afr, bfr, acc, 0, 0, 0);
    }
    accs[nt] = acc;
  }
  __syncthreads();
  u16* Zt = Xt;
#pragma unroll
  for (int nt = 0; nt < 4; ++nt)
#pragma unroll
    for (int r = 0; r < 4; ++r)
      Zt[(wv * 16 + quad * 4 + r) * HSTR + nt * 16 + mrow] = f2b(accs[nt][r]);
  __syncthreads();
  for (int i = tid; i < 2048; i += 256) {
    int n = i >> 5, kk = i & 31;
    int nn = base + n;
    if (nn < NNODES) *(u32*)&z[(size_t)nn * 64 + 2 * kk] = *(u32*)&Zt[n * HSTR + 2 * kk];
  }
}

// ---------------- agg v6: gather + MFMA MLP + fused pooling ---------------

template <bool HAS_NEXT>
__global__ __launch_bounds__(256) void agg_kernel(
    const u16* __restrict__ zin, const float* __restrict__ b1,
    const u16* __restrict__ w2f, const float* __restrict__ b2,
    const u16* __restrict__ w1nf, const float* __restrict__ eps, int li,
    const int* __restrict__ glofs, const int* __restrict__ glcol,
    const int* __restrict__ batch, float* __restrict__ gsum,
    float* __restrict__ gmax, u16* __restrict__ zn) {
  __shared__ u16 w2h[64 * 64];  // fragment order, 8 KB
  __shared__ float b2s[64];
  __shared__ int lofs[65];
  __shared__ int bt[64];
  __shared__ __align__(16) char scratch[2 * 64 * HSTR * 2];  // 18432 B
  int* lcol = (int*)scratch;                  // 9216 B, dead after gather
  u16* H1 = (u16*)scratch;                    // rows 0..63, stride HSTR
  u16* H2 = (u16*)(scratch + 64 * HSTR * 2);  // rows 0..63
  u16* w1nh = (u16*)scratch;                  // aliases H1 after matmul1
  const int tid = threadIdx.x;
  const int lane = tid & 63;
  const int wv = tid >> 6;
  const int sub = lane >> 5;
  const int fl = lane & 31;
  const int f = 2 * fl + sub;
  const int blk = blockIdx.x;
  const int base = ((blk >> 1) << 7) + ((blk & 1) << 6);

  for (int i = tid; i < 512; i += 256) ((int4*)w2h)[i] = ((const int4*)w2f)[i];
  if (tid < 64) {
    b2s[tid] = b2[tid];
    int nn = base + tid;
    bt[tid] = (nn < NNODES) ? batch[nn] : -1;
  }
  if (tid < 65) lofs[tid] = glofs[blk * GOFS + tid];
  __syncthreads();
  const int L = lofs[64];
  {
    int4* ldst = (int4*)lcol;
    const int4* gsrc = (const int4*)(glcol + (size_t)blk * LCAP);
    for (int i = tid; i < (L >> 2); i += 256) ldst[i] = gsrc[i];
  }
  __syncthreads();

  const float e1 = 1.0f + eps[li];
  const float b1v = b1[f];
  const int n0 = wv * 16;

  float av[16];
#pragma unroll 1
  for (int j = 0; j < 16; ++j) {
    int ln = n0 + j;
    int nn = base + ln;
    int sn = (nn < NNODES) ? nn : NNODES;
    int rs = lofs[ln], re = lofs[ln + 1];
    float sa0 = 0.f, sa1 = 0.f, sa2 = 0.f, sa3 = 0.f;
    float sb0 = 0.f, sb1 = 0.f, sb2 = 0.f, sb3 = 0.f;
    for (int e = rs; e < re; e += 16) {
      int c0 = lcol[e + 0 + sub];
      int c1 = lcol[e + 2 + sub];
      int c2 = lcol[e + 4 + sub];
      int c3 = lcol[e + 6 + sub];
      int c4 = lcol[e + 8 + sub];
      int c5 = lcol[e + 10 + sub];
      int c6 = lcol[e + 12 + sub];
      int c7 = lcol[e + 14 + sub];
      u32 v0 = *(const u32*)&zin[(size_t)c0 * 64 + 2 * fl];
      u32 v1 = *(const u32*)&zin[(size_t)c1 * 64 + 2 * fl];
      u32 v2 = *(const u32*)&zin[(size_t)c2 * 64 + 2 * fl];
      u32 v3 = *(const u32*)&zin[(size_t)c3 * 64 + 2 * fl];
      u32 v4 = *(const u32*)&zin[(size_t)c4 * 64 + 2 * fl];
      u32 v5 = *(const u32*)&zin[(size_t)c5 * 64 + 2 * fl];
      u32 v6 = *(const u32*)&zin[(size_t)c6 * 64 + 2 * fl];
      u32 v7 = *(const u32*)&zin[(size_t)c7 * 64 + 2 * fl];
      sa0 += __uint_as_float(v0 << 16);
      sb0 += __uint_as_float(v0 & 0xffff0000u);
      sa1 += __uint_as_float(v1 << 16);
      sb1 += __uint_as_float(v1 & 0xffff0000u);
      sa2 += __uint_as_float(v2 << 16);
      sb2 += __uint_as_float(v2 & 0xffff0000u);
      sa3 += __uint_as_float(v3 << 16);
      sb3 += __uint_as_float(v3 & 0xffff0000u);
      sa0 += __uint_as_float(v4 << 16);
      sb0 += __uint_as_float(v4 & 0xffff0000u);
      sa1 += __uint_as_float(v5 << 16);
      sb1 += __uint_as_float(v5 & 0xffff0000u);
      sa2 += __uint_as_float(v6 << 16);
      sb2 += __uint_as_float(v6 & 0xffff0000u);
      sa3 += __uint_as_float(v7 << 16);
      sb3 += __uint_as_float(v7 & 0xffff0000u);
    }
    float sa = (sa0 + sa1) + (sa2 + sa3);
    float sb = (sb0 + sb1) + (sb2 + sb3);
    sa += __shfl_xor(sa, 32);
    sb += __shfl_xor(sb, 32);
    float sum = sub ? sb : sa;
    float self = b2f(zin[(size_t)sn * 64 + f]);
    av[j] = fmaxf(sum + e1 * self + b1v, 0.f);  // h1
  }
  __syncthreads();  // lcol dead; H1 live
#pragma unroll
  for (int j = 0; j < 16; ++j) H1[(n0 + j) * HSTR + f] = f2b(av[j]);
  LDS_FENCE();  // own-wave rows only: no barrier needed

  const int mrow = lane & 15;
  const int quad = lane >> 4;
  // matmul1: H2 = relu(H1 @ w2 + b2)  (A rows = own wave quarter)
  f32x4 m1[4];
#pragma unroll
  for (int nt = 0; nt < 4; ++nt) {
    f32x4 acc = {0.f, 0.f, 0.f, 0.f};
#pragma unroll
    for (int ks = 0; ks < 2; ++ks) {
      short8 afr = *(const short8*)&H1[(wv * 16 + mrow) * HSTR + ks * 32 + quad * 8];
      short8 bfr = *(const short8*)&w2h[((nt * 2 + ks) * 64 + lane) * 8];
      acc = __builtin_amdgcn_mfma_f32_16x16x32_bf16(afr, bfr, acc, 0, 0, 0);
    }
    m1[nt] = acc;
  }
  LDS_FENCE();
#pragma unroll
  for (int nt = 0; nt < 4; ++nt) {
    float bb = b2s[nt * 16 + mrow];
#pragma unroll
    for (int r = 0; r < 4; ++r)
      H2[(wv * 16 + quad * 4 + r) * HSTR + nt * 16 + mrow] =
          f2b(fmaxf(m1[nt][r] + bb, 0.f));
  }
  LDS_FENCE();

  // fused pooling: own-wave quarter of H2 (rows n0..n0+15), lane = feature
  {
    float s = 0.f, m = 0.f;
    int cur = bt[n0];
#pragma unroll 1
    for (int j = 0; j < 16; ++j) {
      int b = bt[n0 + j];
      if (b != cur) {
        if (cur >= 0) {
          atomicAdd(&gsum[cur * 192 + li * 64 + lane], s);
          atomicMax((u32*)&gmax[cur * 192 + li * 64 + lane], __float_as_uint(m));
        }
        s = 0.f;
        m = 0.f;
        cur = b;
      }
      if (b >= 0) {
        float v = b2f(H2[(n0 + j) * HSTR + lane]);
        s += v;
        m = fmaxf(m, v);
      }
    }
    if (cur >= 0) {
      atomicAdd(&gsum[cur * 192 + li * 64 + lane], s);
      atomicMax((u32*)&gmax[cur * 192 + li * 64 + lane], __float_as_uint(m));
    }
  }

  if (HAS_NEXT) {
    __syncthreads();  // H1 fully dead everywhere; H2 fully written
    for (int i = tid; i < 512; i += 256)
      ((int4*)w1nh)[i] = ((const int4*)w1nf)[i];
    __syncthreads();
    // matmul2: zn = H2 @ w1n (A rows = own quarter); results to regs first
    f32x4 m2[4];
#pragma unroll
    for (int nt = 0; nt < 4; ++nt) {
      f32x4 acc = {0.f, 0.f, 0.f, 0.f};
#pragma unroll
      for (int ks = 0; ks < 2; ++ks) {
        short8 afr = *(const short8*)&H2[(wv * 16 + mrow) * HSTR + ks * 32 + quad * 8];
        short8 bfr = *(const short8*)&w1nh[((nt * 2 + ks) * 64 + lane) * 8];
        acc = __builtin_amdgcn_mfma_f32_16x16x32_bf16(afr, bfr, acc, 0, 0, 0);
      }
      m2[nt] = acc;
    }
    LDS_FENCE();  // all A-reads of own H2 rows done before overwrite
#pragma unroll
    for (int nt = 0; nt < 4; ++nt)
#pragma unroll
      for (int r = 0; r < 4; ++r)
        H2[(wv * 16 + quad * 4 + r) * HSTR + nt * 16 + mrow] = f2b(m2[nt][r]);
    __syncthreads();
    for (int i = tid; i < 2048; i += 256) {
      int n = i >> 5, kk = i & 31;
      int nn = base + n;
      if (nn < NNODES)
        *(u32*)&zn[(size_t)nn * 64 + 2 * kk] = *(u32*)&H2[n * HSTR + 2 * kk];
    }
  }
}

// ---------------- Head: pooled stats -> fc1 -> fc2 -> sigmoid -------------

__global__ __launch_bounds__(256) void head_kernel(
    const float* __restrict__ gsum, const float* __restrict__ gmax,
    const int* __restrict__ gcnt, const float* __restrict__ fc1w,
    const float* __restrict__ fc1b, const float* __restrict__ fc2w,
    const float* __restrict__ fc2b, float* __restrict__ out) {
  __shared__ float gs[4 * 576];
  int tid = threadIdx.x;
  int g0 = blockIdx.x * 4;
  for (int i = tid; i < 4 * 192; i += 256) {
    int w = i / 192, idx = i - w * 192;
    int gi = g0 + w;
    float S = gsum[gi * 192 + idx];
    float M = gmax[gi * 192 + idx];
    float C = (float)gcnt[gi];
    gs[w * 576 + idx] = S / fmaxf(C, 1.0f);
    gs[w * 576 + 192 + idx] = M;
    gs[w * 576 + 384 + idx] = S;
  }
  __syncthreads();
  int wv = tid >> 6, lane = tid & 63;
  int gi = g0 + wv;
  const float* grow = &gs[wv * 576];
  float acc = fc1b[lane];
#pragma unroll 8
  for (int k = 0; k < 576; ++k) acc += grow[k] * fc1w[k * 64 + lane];
  acc = fmaxf(acc, 0.f);
  float p0 = acc * fc2w[lane * 2 + 0];
  float p1 = acc * fc2w[lane * 2 + 1];
  for (int off = 32; off; off >>= 1) {
    p0 += __shfl_down(p0, off);
    p1 += __shfl_down(p1, off);
  }
  if (lane == 0) {
    out[gi * 2 + 0] = 1.f / (1.f + __expf(-(p0 + fc2b[0])));
    out[gi * 2 + 1] = 1.f / (1.f + __expf(-(p1 + fc2b[1])));
  }
}

// ---------------- launch ----------------

extern "C" void kernel_launch(void* const* d_in, const int* in_sizes, int n_in,
                              void* d_out, int out_size, void* d_ws,
                              size_t ws_size, hipStream_t stream) {
  const float* x = (const float*)d_in[0];
  const int* ei = (const int*)d_in[1];
  const int* src = ei;
  const int* dst = ei + NEDGES;
  const int* batch = (const int*)d_in[2];
  const float* lw1[3] = {(const float*)d_in[3], (const float*)d_in[7],
                         (const float*)d_in[11]};
  const float* lb1[3] = {(const float*)d_in[4], (const float*)d_in[8],
                         (const float*)d_in[12]};
  const float* lw2[3] = {(const float*)d_in[5], (const float*)d_in[9],
                         (const float*)d_in[13]};
  const float* lb2[3] = {(const float*)d_in[6], (const float*)d_in[10],
                         (const float*)d_in[14]};
  const float* eps = (const float*)d_in[15];
  const float* fc1w = (const float*)d_in[16];
  const float* fc1b = (const float*)d_in[17];
  const float* fc2w = (const float*)d_in[18];
  const float* fc2b = (const float*)d_in[19];
  float* out = (float*)d_out;

  char* p = (char*)d_ws;
  auto carve = [&](size_t bytes) {
    void* r = (void*)p;
    p += (bytes + 1023) & ~(size_t)1023;
    return r;
  };
  int* gcur = (int*)carve((NB + 4) * 4);
  int* st = (int*)carve((size_t)NB * BCAP * 4);
  int* glofs = (int*)carve((size_t)NBH * GOFS * 4);
  int* glcol = (int*)carve((size_t)NBH * LCAP * 4);
  u16* w1f = (u16*)carve(8192 * 2);
  u16* w2f0 = (u16*)carve(4096 * 2);
  u16* w2f1 = (u16*)carve(4096 * 2);
  u16* w2f2 = (u16*)carve(4096 * 2);
  u16* w1nf1 = (u16*)carve(4096 * 2);
  u16* w1nf2 = (u16*)carve(4096 * 2);
  u16* zA = (u16*)carve((size_t)(NNODES + 1) * 64 * 2);
  u16* zB = (u16*)carve((size_t)(NNODES + 1) * 64 * 2);
  float* gsum = (float*)carve((size_t)NGRAPHS * 192 * 4);  // 393216, 1024-mult
  float* gmax = (float*)carve((size_t)NGRAPHS * 192 * 4);
  int* gcnt = (int*)carve(NGRAPHS * 4);

  init_kernel<<<4, 256, 0, stream>>>(gcur, zA, zB);
  hipMemsetAsync(gsum, 0, (size_t)NGRAPHS * 192 * 4 * 2 + NGRAPHS * 4, stream);
  bin_kernel<<<NCHUNKS, 512, 0, stream>>>(src, dst, gcur, st);
  csr_kernel<<<NBH, 256, 0, stream>>>(gcur, st, glofs, glcol);
  prep_kernel<<<6, 256, 0, stream>>>(lw1[0], lw2[0], lw2[1], lw2[2], lw1[1],
                                     lw1[2], w1f, w2f0, w2f1, w2f2, w1nf1,
                                     w1nf2);
  cnt_kernel<<<98, 1024, 0, stream>>>(batch, gcnt);

  gemm128_kernel<<<1563, 256, 0, stream>>>(x, w1f, zA);

  agg_kernel<true><<<NBH, 256, 0, stream>>>(zA, lb1[0], w2f0, lb2[0], w1nf1,
                                            eps, 0, glofs, glcol, batch, gsum,
                                            gmax, zB);
  agg_kernel<true><<<NBH, 256, 0, stream>>>(zB, lb1[1], w2f1, lb2[1], w1nf2,
                                            eps, 1, glofs, glcol, batch, gsum,
                                            gmax, zA);
  agg_kernel<false><<<NBH, 256, 0, stream>>>(zA, lb1[2], w2f2, lb2[2],
                                             (const u16*)nullptr, eps, 2, glofs,
                                             glcol, batch, gsum, gmax,
                                             (u16*)nullptr);

  head_kernel<<<NGRAPHS / 4, 256, 0, stream>>>(gsum, gmax, gcnt, fc1w, fc1b,
                                               fc2w, fc2b, out);
}

// Round 10
// 358.002 us; speedup vs baseline: 6.9789x; 1.1595x over previous
//
#include <hip/hip_runtime.h>
#include <math.h>

// GIN v6.1: identical to v6 except cnt_kernel: sorted batch -> per-graph
// counts via binary search (512 searches) instead of 100k contended global
// atomics (R9: 69us -> ~3us; sorted input serialized all atomics on ~2 lines).

#define NNODES 100000
#define NEDGES 1600000
#define NGRAPHS 512
#define NB 782
#define NBH 1564
#define BCAP 2560
#define LCAP 2304
#define GOFS 72
#define CHUNK 4096
#define NCHUNKS 391
#define HSTR 72   // H1/H2 row stride (u16): 144B, 36 dwords = 4 mod 32
#define XSTR 136  // gemm x-tile row stride (u16)

typedef unsigned short u16;
typedef unsigned int u32;
typedef __attribute__((ext_vector_type(8))) short short8;
typedef __attribute__((ext_vector_type(4))) float f32x4;

__device__ __forceinline__ u16 f2b(float f) {
  union { float f; unsigned u; } v;
  v.f = f;
  unsigned r = v.u + 0x7FFF + ((v.u >> 16) & 1);
  return (u16)(r >> 16);
}
__device__ __forceinline__ float b2f(u16 h) {
  union { unsigned u; float f; } v;
  v.u = ((unsigned)h) << 16;
  return v.f;
}
#define LDS_FENCE() __asm__ volatile("s_waitcnt lgkmcnt(0)" ::: "memory")

// ---------------- init ----------------

__global__ __launch_bounds__(256) void init_kernel(int* __restrict__ gcur,
                                                   u16* __restrict__ zA,
                                                   u16* __restrict__ zB) {
  int i = blockIdx.x * 256 + threadIdx.x;
  if (i < NB) gcur[i] = i * BCAP;
  if (blockIdx.x == 3) {
    int t = threadIdx.x;
    if (t < 64) zA[(size_t)NNODES * 64 + t] = 0;
    else if (t < 128) zB[(size_t)NNODES * 64 + (t - 64)] = 0;
  }
}

// ---------------- per-graph node counts (binary search, batch sorted) -----

__device__ __forceinline__ int lb_dev(const int* __restrict__ a, int n, int v) {
  int lo = 0, hi = n;
  while (lo < hi) {
    int m = (lo + hi) >> 1;
    if (a[m] < v)
      lo = m + 1;
    else
      hi = m;
  }
  return lo;
}

__global__ __launch_bounds__(256) void cnt_kernel(const int* __restrict__ batch,
                                                  int* __restrict__ gcnt) {
  int g = blockIdx.x * 256 + threadIdx.x;
  if (g < NGRAPHS)
    gcnt[g] = lb_dev(batch, NNODES, g + 1) - lb_dev(batch, NNODES, g);
}

// ---------------- weight pre-swizzle to MFMA B-fragment order -------------

__global__ __launch_bounds__(256) void prep_kernel(
    const float* __restrict__ w1g, const float* __restrict__ w2a,
    const float* __restrict__ w2b, const float* __restrict__ w2c,
    const float* __restrict__ w1b, const float* __restrict__ w1c,
    u16* __restrict__ w1f, u16* __restrict__ w2fa, u16* __restrict__ w2fb,
    u16* __restrict__ w2fc, u16* __restrict__ w1nfb, u16* __restrict__ w1nfc) {
  int blk = blockIdx.x, tid = threadIdx.x;
  if (blk == 0) {  // 128x64
    for (int i = tid; i < 8192; i += 256) {
      int jj = i & 7, lane = (i >> 3) & 63, c = i >> 9;
      int nt = c >> 2, ks = c & 3;
      int mrow = lane & 15, quad = lane >> 4;
      w1f[i] = f2b(w1g[(ks * 32 + quad * 8 + jj) * 64 + nt * 16 + mrow]);
    }
  } else {  // 64x64
    const float* s = (blk == 1) ? w2a : (blk == 2) ? w2b : (blk == 3) ? w2c
                    : (blk == 4) ? w1b : w1c;
    u16* d = (blk == 1) ? w2fa : (blk == 2) ? w2fb : (blk == 3) ? w2fc
             : (blk == 4) ? w1nfb : w1nfc;
    for (int i = tid; i < 4096; i += 256) {
      int jj = i & 7, lane = (i >> 3) & 63, c = i >> 9;
      int nt = c >> 1, ks = c & 1;
      int mrow = lane & 15, quad = lane >> 4;
      d[i] = f2b(s[(ks * 32 + quad * 8 + jj) * 64 + nt * 16 + mrow]);
    }
  }
}

// ---------------- binned scatter ----------------

__global__ __launch_bounds__(512) void bin_kernel(const int* __restrict__ src,
                                                  const int* __restrict__ dst,
                                                  int* __restrict__ gcur,
                                                  int* __restrict__ st) {
  __shared__ int hist[NB];
  __shared__ int lofs[NB + 1];
  __shared__ int lcur[NB];
  __shared__ int gbase[NB];
  __shared__ int sd[1024];
  __shared__ int staged[CHUNK];
  __shared__ u16 stb[CHUNK];
  const int t = threadIdx.x;
  const int e0 = blockIdx.x * CHUNK;
  const int n = min(CHUNK, NEDGES - e0);

  for (int i = t; i < NB; i += 512) hist[i] = 0;
  __syncthreads();

  int pk[8];
  int bk[8];
#pragma unroll
  for (int k = 0; k < 8; ++k) {
    int i = t + k * 512;
    if (i < n) {
      int s = src[e0 + i];
      int d = dst[e0 + i];
      int b = d >> 7;
      pk[k] = (s << 7) | (d & 127);
      bk[k] = b;
      atomicAdd(&hist[b], 1);
    } else {
      bk[k] = -1;
    }
  }
  __syncthreads();

  sd[t] = (t < NB) ? hist[t] : 0;
  sd[t + 512] = (t + 512 < NB) ? hist[t + 512] : 0;
  __syncthreads();
  for (int off = 1; off < 1024; off <<= 1) {
    int v0 = (t >= off) ? sd[t - off] : 0;
    int v1 = (t + 512 >= off) ? sd[t + 512 - off] : 0;
    __syncthreads();
    sd[t] += v0;
    sd[t + 512] += v1;
    __syncthreads();
  }
  if (t == 0) lofs[0] = 0;
  for (int i = t; i < NB; i += 512) {
    int inc = sd[i];
    int c = hist[i];
    lofs[i + 1] = inc;
    lcur[i] = inc - c;
    gbase[i] = c ? atomicAdd(&gcur[i], c) : 0;
  }
  __syncthreads();

#pragma unroll
  for (int k = 0; k < 8; ++k) {
    if (bk[k] >= 0) {
      int r = atomicAdd(&lcur[bk[k]], 1);
      staged[r] = pk[k];
      stb[r] = (u16)bk[k];
    }
  }
  __syncthreads();

  for (int i = t; i < n; i += 512) {
    int b = stb[i];
    st[gbase[b] + (i - lofs[b])] = staged[i];
  }
}

// ---------------- CSR build (once) ----------------

__global__ __launch_bounds__(256) void csr_kernel(const int* __restrict__ gcur,
                                                  const int* __restrict__ st,
                                                  int* __restrict__ glofs,
                                                  int* __restrict__ glcol) {
  __shared__ int lcol[LCAP];
  __shared__ int lhist[64];
  __shared__ int lofs[65];
  __shared__ int lcur[64];
  __shared__ int ssc[64];
  const int tid = threadIdx.x;
  const int blk = blockIdx.x;
  const int bkt = blk >> 1;
  const int half = blk & 1;
  const int ofs = bkt * BCAP;
  const int cnt = min(gcur[bkt] - ofs, BCAP);

  if (tid < 64) lhist[tid] = 0;
  __syncthreads();
  for (int i = tid; i < cnt; i += 256) {
    int d7 = st[ofs + i] & 127;
    if ((d7 >> 6) == half) atomicAdd(&lhist[d7 & 63], 1);
  }
  __syncthreads();
  if (tid < 64) ssc[tid] = (lhist[tid] + 15) & ~15;
  __syncthreads();
  for (int off = 1; off < 64; off <<= 1) {
    int v = (tid < 64 && tid >= off) ? ssc[tid - off] : 0;
    __syncthreads();
    if (tid < 64) ssc[tid] += v;
    __syncthreads();
  }
  if (tid < 64) {
    lofs[tid + 1] = ssc[tid];
    lcur[tid] = ssc[tid] - ((lhist[tid] + 15) & ~15);
  }
  if (tid == 0) lofs[0] = 0;
  __syncthreads();
  for (int i = tid; i < cnt; i += 256) {
    int p = st[ofs + i];
    int d7 = p & 127;
    if ((d7 >> 6) == half) {
      int r = atomicAdd(&lcur[d7 & 63], 1);
      if (r < LCAP) lcol[r] = p >> 7;
    }
  }
  __syncthreads();
  if (tid < 64) {
    int re = min(lofs[tid + 1], LCAP);
    for (int r = lcur[tid]; r < re; ++r) lcol[r] = NNODES;
  }
  __syncthreads();
  if (tid < 65) glofs[blk * GOFS + tid] = min(lofs[tid], LCAP);
  int L = min(lofs[64], LCAP);
  int4* gdst = (int4*)(glcol + (size_t)blk * LCAP);
  const int4* lsrc = (const int4*)lcol;
  for (int i = tid; i < (L >> 2); i += 256) gdst[i] = lsrc[i];
}

// ---------------- GEMM (MFMA): z = x(Nx128) @ w1, z bf16 ----------------

__global__ __launch_bounds__(256) void gemm128_kernel(
    const float* __restrict__ x, const u16* __restrict__ w1f,
    u16* __restrict__ z) {
  __shared__ u16 w1h[128 * 64];  // fragment order, 16 KB
  __shared__ u16 Xt[64 * XSTR];  // 17 KB; reused as z-tile
  const int tid = threadIdx.x;
  const int base = blockIdx.x * 64;
  for (int i = tid; i < 1024; i += 256) ((int4*)w1h)[i] = ((const int4*)w1f)[i];
  for (int i = tid; i < 2048; i += 256) {
    int n = i >> 5, c4 = i & 31;
    int nn = base + n;
    float4 v = make_float4(0.f, 0.f, 0.f, 0.f);
    if (nn < NNODES) v = *(const float4*)&x[(size_t)nn * 128 + 4 * c4];
    u32 p0 = (u32)f2b(v.x) | ((u32)f2b(v.y) << 16);
    u32 p1 = (u32)f2b(v.z) | ((u32)f2b(v.w) << 16);
    *(u32*)&Xt[n * XSTR + 4 * c4] = p0;
    *(u32*)&Xt[n * XSTR + 4 * c4 + 2] = p1;
  }
  __syncthreads();
  const int lane = tid & 63;
  const int wv = tid >> 6;
  const int mrow = lane & 15;
  const int quad = lane >> 4;
  f32x4 accs[4];
#pragma unroll
  for (int nt = 0; nt < 4; ++nt) {
    f32x4 acc = {0.f, 0.f, 0.f, 0.f};
#pragma unroll
    for (int ks = 0; ks < 4; ++ks) {
      short8 afr = *(const short8*)&Xt[(wv * 16 + mrow) * XSTR + ks * 32 + quad * 8];
      short8 bfr = *(const short8*)&w1h[((nt * 4 + ks) * 64 + lane) * 8];
      acc = __builtin_amdgcn_mfma_f32_16x16x32_bf16(afr, bfr, acc, 0, 0, 0);
    }
    accs[nt] = acc;
  }
  __syncthreads();
  u16* Zt = Xt;
#pragma unroll
  for (int nt = 0; nt < 4; ++nt)
#pragma unroll
    for (int r = 0; r < 4; ++r)
      Zt[(wv * 16 + quad * 4 + r) * HSTR + nt * 16 + mrow] = f2b(accs[nt][r]);
  __syncthreads();
  for (int i = tid; i < 2048; i += 256) {
    int n = i >> 5, kk = i & 31;
    int nn = base + n;
    if (nn < NNODES) *(u32*)&z[(size_t)nn * 64 + 2 * kk] = *(u32*)&Zt[n * HSTR + 2 * kk];
  }
}

// ---------------- agg v6: gather + MFMA MLP + fused pooling ---------------

template <bool HAS_NEXT>
__global__ __launch_bounds__(256) void agg_kernel(
    const u16* __restrict__ zin, const float* __restrict__ b1,
    const u16* __restrict__ w2f, const float* __restrict__ b2,
    const u16* __restrict__ w1nf, const float* __restrict__ eps, int li,
    const int* __restrict__ glofs, const int* __restrict__ glcol,
    const int* __restrict__ batch, float* __restrict__ gsum,
    float* __restrict__ gmax, u16* __restrict__ zn) {
  __shared__ u16 w2h[64 * 64];  // fragment order, 8 KB
  __shared__ float b2s[64];
  __shared__ int lofs[65];
  __shared__ int bt[64];
  __shared__ __align__(16) char scratch[2 * 64 * HSTR * 2];  // 18432 B
  int* lcol = (int*)scratch;                  // 9216 B, dead after gather
  u16* H1 = (u16*)scratch;                    // rows 0..63, stride HSTR
  u16* H2 = (u16*)(scratch + 64 * HSTR * 2);  // rows 0..63
  u16* w1nh = (u16*)scratch;                  // aliases H1 after matmul1
  const int tid = threadIdx.x;
  const int lane = tid & 63;
  const int wv = tid >> 6;
  const int sub = lane >> 5;
  const int fl = lane & 31;
  const int f = 2 * fl + sub;
  const int blk = blockIdx.x;
  const int base = ((blk >> 1) << 7) + ((blk & 1) << 6);

  for (int i = tid; i < 512; i += 256) ((int4*)w2h)[i] = ((const int4*)w2f)[i];
  if (tid < 64) {
    b2s[tid] = b2[tid];
    int nn = base + tid;
    bt[tid] = (nn < NNODES) ? batch[nn] : -1;
  }
  if (tid < 65) lofs[tid] = glofs[blk * GOFS + tid];
  __syncthreads();
  const int L = lofs[64];
  {
    int4* ldst = (int4*)lcol;
    const int4* gsrc = (const int4*)(glcol + (size_t)blk * LCAP);
    for (int i = tid; i < (L >> 2); i += 256) ldst[i] = gsrc[i];
  }
  __syncthreads();

  const float e1 = 1.0f + eps[li];
  const float b1v = b1[f];
  const int n0 = wv * 16;

  float av[16];
#pragma unroll 1
  for (int j = 0; j < 16; ++j) {
    int ln = n0 + j;
    int nn = base + ln;
    int sn = (nn < NNODES) ? nn : NNODES;
    int rs = lofs[ln], re = lofs[ln + 1];
    float sa0 = 0.f, sa1 = 0.f, sa2 = 0.f, sa3 = 0.f;
    float sb0 = 0.f, sb1 = 0.f, sb2 = 0.f, sb3 = 0.f;
    for (int e = rs; e < re; e += 16) {
      int c0 = lcol[e + 0 + sub];
      int c1 = lcol[e + 2 + sub];
      int c2 = lcol[e + 4 + sub];
      int c3 = lcol[e + 6 + sub];
      int c4 = lcol[e + 8 + sub];
      int c5 = lcol[e + 10 + sub];
      int c6 = lcol[e + 12 + sub];
      int c7 = lcol[e + 14 + sub];
      u32 v0 = *(const u32*)&zin[(size_t)c0 * 64 + 2 * fl];
      u32 v1 = *(const u32*)&zin[(size_t)c1 * 64 + 2 * fl];
      u32 v2 = *(const u32*)&zin[(size_t)c2 * 64 + 2 * fl];
      u32 v3 = *(const u32*)&zin[(size_t)c3 * 64 + 2 * fl];
      u32 v4 = *(const u32*)&zin[(size_t)c4 * 64 + 2 * fl];
      u32 v5 = *(const u32*)&zin[(size_t)c5 * 64 + 2 * fl];
      u32 v6 = *(const u32*)&zin[(size_t)c6 * 64 + 2 * fl];
      u32 v7 = *(const u32*)&zin[(size_t)c7 * 64 + 2 * fl];
      sa0 += __uint_as_float(v0 << 16);
      sb0 += __uint_as_float(v0 & 0xffff0000u);
      sa1 += __uint_as_float(v1 << 16);
      sb1 += __uint_as_float(v1 & 0xffff0000u);
      sa2 += __uint_as_float(v2 << 16);
      sb2 += __uint_as_float(v2 & 0xffff0000u);
      sa3 += __uint_as_float(v3 << 16);
      sb3 += __uint_as_float(v3 & 0xffff0000u);
      sa0 += __uint_as_float(v4 << 16);
      sb0 += __uint_as_float(v4 & 0xffff0000u);
      sa1 += __uint_as_float(v5 << 16);
      sb1 += __uint_as_float(v5 & 0xffff0000u);
      sa2 += __uint_as_float(v6 << 16);
      sb2 += __uint_as_float(v6 & 0xffff0000u);
      sa3 += __uint_as_float(v7 << 16);
      sb3 += __uint_as_float(v7 & 0xffff0000u);
    }
    float sa = (sa0 + sa1) + (sa2 + sa3);
    float sb = (sb0 + sb1) + (sb2 + sb3);
    sa += __shfl_xor(sa, 32);
    sb += __shfl_xor(sb, 32);
    float sum = sub ? sb : sa;
    float self = b2f(zin[(size_t)sn * 64 + f]);
    av[j] = fmaxf(sum + e1 * self + b1v, 0.f);  // h1
  }
  __syncthreads();  // lcol dead; H1 live
#pragma unroll
  for (int j = 0; j < 16; ++j) H1[(n0 + j) * HSTR + f] = f2b(av[j]);
  LDS_FENCE();  // own-wave rows only: no barrier needed

  const int mrow = lane & 15;
  const int quad = lane >> 4;
  // matmul1: H2 = relu(H1 @ w2 + b2)  (A rows = own wave quarter)
  f32x4 m1[4];
#pragma unroll
  for (int nt = 0; nt < 4; ++nt) {
    f32x4 acc = {0.f, 0.f, 0.f, 0.f};
#pragma unroll
    for (int ks = 0; ks < 2; ++ks) {
      short8 afr = *(const short8*)&H1[(wv * 16 + mrow) * HSTR + ks * 32 + quad * 8];
      short8 bfr = *(const short8*)&w2h[((nt * 2 + ks) * 64 + lane) * 8];
      acc = __builtin_amdgcn_mfma_f32_16x16x32_bf16(afr, bfr, acc, 0, 0, 0);
    }
    m1[nt] = acc;
  }
  LDS_FENCE();
#pragma unroll
  for (int nt = 0; nt < 4; ++nt) {
    float bb = b2s[nt * 16 + mrow];
#pragma unroll
    for (int r = 0; r < 4; ++r)
      H2[(wv * 16 + quad * 4 + r) * HSTR + nt * 16 + mrow] =
          f2b(fmaxf(m1[nt][r] + bb, 0.f));
  }
  LDS_FENCE();

  // fused pooling: own-wave quarter of H2 (rows n0..n0+15), lane = feature
  {
    float s = 0.f, m = 0.f;
    int cur = bt[n0];
#pragma unroll 1
    for (int j = 0; j < 16; ++j) {
      int b = bt[n0 + j];
      if (b != cur) {
        if (cur >= 0) {
          atomicAdd(&gsum[cur * 192 + li * 64 + lane], s);
          atomicMax((u32*)&gmax[cur * 192 + li * 64 + lane], __float_as_uint(m));
        }
        s = 0.f;
        m = 0.f;
        cur = b;
      }
      if (b >= 0) {
        float v = b2f(H2[(n0 + j) * HSTR + lane]);
        s += v;
        m = fmaxf(m, v);
      }
    }
    if (cur >= 0) {
      atomicAdd(&gsum[cur * 192 + li * 64 + lane], s);
      atomicMax((u32*)&gmax[cur * 192 + li * 64 + lane], __float_as_uint(m));
    }
  }

  if (HAS_NEXT) {
    __syncthreads();  // H1 fully dead everywhere; H2 fully written
    for (int i = tid; i < 512; i += 256)
      ((int4*)w1nh)[i] = ((const int4*)w1nf)[i];
    __syncthreads();
    // matmul2: zn = H2 @ w1n (A rows = own quarter); results to regs first
    f32x4 m2[4];
#pragma unroll
    for (int nt = 0; nt < 4; ++nt) {
      f32x4 acc = {0.f, 0.f, 0.f, 0.f};
#pragma unroll
      for (int ks = 0; ks < 2; ++ks) {
        short8 afr = *(const short8*)&H2[(wv * 16 + mrow) * HSTR + ks * 32 + quad * 8];
        short8 bfr = *(const short8*)&w1nh[((nt * 2 + ks) * 64 + lane) * 8];
        acc = __builtin_amdgcn_mfma_f32_16x16x32_bf16(afr, bfr, acc, 0, 0, 0);
      }
      m2[nt] = acc;
    }
    LDS_FENCE();  // all A-reads of own H2 rows done before overwrite
#pragma unroll
    for (int nt = 0; nt < 4; ++nt)
#pragma unroll
      for (int r = 0; r < 4; ++r)
        H2[(wv * 16 + quad * 4 + r) * HSTR + nt * 16 + mrow] = f2b(m2[nt][r]);
    __syncthreads();
    for (int i = tid; i < 2048; i += 256) {
      int n = i >> 5, kk = i & 31;
      int nn = base + n;
      if (nn < NNODES)
        *(u32*)&zn[(size_t)nn * 64 + 2 * kk] = *(u32*)&H2[n * HSTR + 2 * kk];
    }
  }
}

// ---------------- Head: pooled stats -> fc1 -> fc2 -> sigmoid -------------

__global__ __launch_bounds__(256) void head_kernel(
    const float* __restrict__ gsum, const float* __restrict__ gmax,
    const int* __restrict__ gcnt, const float* __restrict__ fc1w,
    const float* __restrict__ fc1b, const float* __restrict__ fc2w,
    const float* __restrict__ fc2b, float* __restrict__ out) {
  __shared__ float gs[4 * 576];
  int tid = threadIdx.x;
  int g0 = blockIdx.x * 4;
  for (int i = tid; i < 4 * 192; i += 256) {
    int w = i / 192, idx = i - w * 192;
    int gi = g0 + w;
    float S = gsum[gi * 192 + idx];
    float M = gmax[gi * 192 + idx];
    float C = (float)gcnt[gi];
    gs[w * 576 + idx] = S / fmaxf(C, 1.0f);
    gs[w * 576 + 192 + idx] = M;
    gs[w * 576 + 384 + idx] = S;
  }
  __syncthreads();
  int wv = tid >> 6, lane = tid & 63;
  int gi = g0 + wv;
  const float* grow = &gs[wv * 576];
  float acc = fc1b[lane];
#pragma unroll 8
  for (int k = 0; k < 576; ++k) acc += grow[k] * fc1w[k * 64 + lane];
  acc = fmaxf(acc, 0.f);
  float p0 = acc * fc2w[lane * 2 + 0];
  float p1 = acc * fc2w[lane * 2 + 1];
  for (int off = 32; off; off >>= 1) {
    p0 += __shfl_down(p0, off);
    p1 += __shfl_down(p1, off);
  }
  if (lane == 0) {
    out[gi * 2 + 0] = 1.f / (1.f + __expf(-(p0 + fc2b[0])));
    out[gi * 2 + 1] = 1.f / (1.f + __expf(-(p1 + fc2b[1])));
  }
}

// ---------------- launch ----------------

extern "C" void kernel_launch(void* const* d_in, const int* in_sizes, int n_in,
                              void* d_out, int out_size, void* d_ws,
                              size_t ws_size, hipStream_t stream) {
  const float* x = (const float*)d_in[0];
  const int* ei = (const int*)d_in[1];
  const int* src = ei;
  const int* dst = ei + NEDGES;
  const int* batch = (const int*)d_in[2];
  const float* lw1[3] = {(const float*)d_in[3], (const float*)d_in[7],
                         (const float*)d_in[11]};
  const float* lb1[3] = {(const float*)d_in[4], (const float*)d_in[8],
                         (const float*)d_in[12]};
  const float* lw2[3] = {(const float*)d_in[5], (const float*)d_in[9],
                         (const float*)d_in[13]};
  const float* lb2[3] = {(const float*)d_in[6], (const float*)d_in[10],
                         (const float*)d_in[14]};
  const float* eps = (const float*)d_in[15];
  const float* fc1w = (const float*)d_in[16];
  const float* fc1b = (const float*)d_in[17];
  const float* fc2w = (const float*)d_in[18];
  const float* fc2b = (const float*)d_in[19];
  float* out = (float*)d_out;

  char* p = (char*)d_ws;
  auto carve = [&](size_t bytes) {
    void* r = (void*)p;
    p += (bytes + 1023) & ~(size_t)1023;
    return r;
  };
  int* gcur = (int*)carve((NB + 4) * 4);
  int* st = (int*)carve((size_t)NB * BCAP * 4);
  int* glofs = (int*)carve((size_t)NBH * GOFS * 4);
  int* glcol = (int*)carve((size_t)NBH * LCAP * 4);
  u16* w1f = (u16*)carve(8192 * 2);
  u16* w2f0 = (u16*)carve(4096 * 2);
  u16* w2f1 = (u16*)carve(4096 * 2);
  u16* w2f2 = (u16*)carve(4096 * 2);
  u16* w1nf1 = (u16*)carve(4096 * 2);
  u16* w1nf2 = (u16*)carve(4096 * 2);
  u16* zA = (u16*)carve((size_t)(NNODES + 1) * 64 * 2);
  u16* zB = (u16*)carve((size_t)(NNODES + 1) * 64 * 2);
  float* gsum = (float*)carve((size_t)NGRAPHS * 192 * 4);
  float* gmax = (float*)carve((size_t)NGRAPHS * 192 * 4);
  int* gcnt = (int*)carve(NGRAPHS * 4);

  init_kernel<<<4, 256, 0, stream>>>(gcur, zA, zB);
  hipMemsetAsync(gsum, 0, (size_t)NGRAPHS * 192 * 4 * 2, stream);
  bin_kernel<<<NCHUNKS, 512, 0, stream>>>(src, dst, gcur, st);
  csr_kernel<<<NBH, 256, 0, stream>>>(gcur, st, glofs, glcol);
  prep_kernel<<<6, 256, 0, stream>>>(lw1[0], lw2[0], lw2[1], lw2[2], lw1[1],
                                     lw1[2], w1f, w2f0, w2f1, w2f2, w1nf1,
                                     w1nf2);
  cnt_kernel<<<2, 256, 0, stream>>>(batch, gcnt);

  gemm128_kernel<<<1563, 256, 0, stream>>>(x, w1f, zA);

  agg_kernel<true><<<NBH, 256, 0, stream>>>(zA, lb1[0], w2f0, lb2[0], w1nf1,
                                            eps, 0, glofs, glcol, batch, gsum,
                                            gmax, zB);
  agg_kernel<true><<<NBH, 256, 0, stream>>>(zB, lb1[1], w2f1, lb2[1], w1nf2,
                                            eps, 1, glofs, glcol, batch, gsum,
                                            gmax, zA);
  agg_kernel<false><<<NBH, 256, 0, stream>>>(zA, lb1[2], w2f2, lb2[2],
                                             (const u16*)nullptr, eps, 2, glofs,
                                             glcol, batch, gsum, gmax,
                                             (u16*)nullptr);

  head_kernel<<<NGRAPHS / 4, 256, 0, stream>>>(gsum, gmax, gcnt, fc1w, fc1b,
                                               fc2w, fc2b, out);
}